// Round 9
// baseline (108.824 us; speedup 1.0000x reference)
//
#include <hip/hip_runtime.h>

typedef unsigned short u16;
typedef unsigned int   u32;
typedef __attribute__((ext_vector_type(8))) short bf16x8;
typedef __attribute__((ext_vector_type(4))) float f32x4;

#define BB 2
#define SS 4096
#define DD 768
#define HH 12
#define FF 3072
#define NTOK 8192

#define GLDS16(gp, lp) __builtin_amdgcn_global_load_lds(                      \
    (const __attribute__((address_space(1))) u32*)(gp),                       \
    (__attribute__((address_space(3))) u32*)(lp), 16, 0, 0)

__device__ __forceinline__ float bf2f(u16 u) {
  return __uint_as_float(((u32)u) << 16);
}
__device__ __forceinline__ u16 f2bf(float f) {
  u32 x = __float_as_uint(f);
  x = x + 0x7FFFu + ((x >> 16) & 1u);
  return (u16)(x >> 16);
}
__device__ __forceinline__ float gelu_f(float v) {
  return 0.5f * v * (1.0f + erff(v * 0.70710678118654752f));
}

template<bool MAXOP>
__device__ __forceinline__ float blk_reduce(float v, float* sbuf) {
  #pragma unroll
  for (int o = 32; o > 0; o >>= 1) {
    float t = __shfl_xor(v, o, 64);
    v = MAXOP ? fmaxf(v, t) : (v + t);
  }
  int wave = threadIdx.x >> 6;
  int nw = blockDim.x >> 6;
  __syncthreads();
  if ((threadIdx.x & 63) == 0) sbuf[wave] = v;
  __syncthreads();
  float r = sbuf[0];
  for (int i = 1; i < nw; i++) r = MAXOP ? fmaxf(r, sbuf[i]) : (r + sbuf[i]);
  return r;
}

// ---- K1: blocks <8192: x = LN(emb[sent]+pos) -> bf16.
//          blocks >=8192: transpose+cvt wk/wv (1152 tiles); block 8192 also seeds. ----
__global__ __launch_bounds__(192) void embed_ln_k(const int* __restrict__ sent,
    const float* __restrict__ emb, const float* __restrict__ pos,
    const float* __restrict__ g, const float* __restrict__ be, u16* __restrict__ xout,
    const float* __restrict__ wk, const float* __restrict__ wv,
    u16* __restrict__ wkT, u16* __restrict__ wvT,
    const int* sp, const int* ep, const float* bq, const float* bo,
    const float* b1, const float* b2,
    float* qg, float* oa, float* f1, float* f2, int* gidx) {
  int tid = threadIdx.x;
  int bid = blockIdx.x;
  if (bid >= NTOK) {
    // ---- transcvt role ----
    int t = bid - NTOK;                 // 0..1151
    if (t == 0) {                       // seed (once)
      if (tid < 4) {
        int b = tid >> 1;
        int s = (tid & 1) ? ep[b] : sp[b];
        gidx[tid] = b * SS + s;
      }
      for (int i = tid; i < DD; i += 192) {
        float vq = bq[i], vo = bo[i], v2 = b2[i];
        #pragma unroll
        for (int r = 0; r < 4; r++) {
          qg[r * DD + i] = vq; oa[r * DD + i] = vo; f2[r * DD + i] = v2;
        }
      }
      for (int i = tid; i < FF; i += 192) {
        float v1 = b1[i];
        #pragma unroll
        for (int r = 0; r < 4; r++) f1[r * FF + i] = v1;
      }
    }
    int z = t >= 576;
    int tt = z ? t - 576 : t;
    const float* W = z ? wv : wk;
    u16* WT = z ? wvT : wkT;
    __shared__ float tld[32][33];
    int n0 = (tt % 24) * 32, k0 = (tt / 24) * 32;
    int tx = tid & 31, ty = tid >> 5;   // 32 x 6
    #pragma unroll
    for (int i = 0; i < 6; i++) {
      int row = ty + i * 6;
      if (row < 32)
        tld[row][tx] = W[(size_t)(k0 + row) * DD + n0 + tx];
    }
    __syncthreads();
    #pragma unroll
    for (int i = 0; i < 6; i++) {
      int row = ty + i * 6;
      if (row < 32)
        WT[(size_t)(n0 + row) * DD + k0 + tx] = f2bf(tld[tx][row]);
    }
    return;
  }
  // ---- embed+LN role ----
  __shared__ float sbuf[8];
  int tok = bid;
  int s = tok & (SS - 1);
  int row = sent[tok];
  float4 e = *(const float4*)(emb + (size_t)row * DD + tid * 4);
  float4 p = *(const float4*)(pos + (size_t)s * DD + tid * 4);
  float v0 = e.x + p.x, v1 = e.y + p.y, v2 = e.z + p.z, v3 = e.w + p.w;
  float sum = v0 + v1 + v2 + v3;
  float sq  = v0 * v0 + v1 * v1 + v2 * v2 + v3 * v3;
  sum = blk_reduce<false>(sum, sbuf);
  sq  = blk_reduce<false>(sq, sbuf);
  float mean = sum * (1.f / DD);
  float var  = sq * (1.f / DD) - mean * mean;
  float rstd = rsqrtf(var + 1e-5f);
  float4 gg = *(const float4*)(g + tid * 4);
  float4 bb = *(const float4*)(be + tid * 4);
  float o0 = (v0 - mean) * rstd * gg.x + bb.x;
  float o1 = (v1 - mean) * rstd * gg.y + bb.y;
  float o2 = (v2 - mean) * rstd * gg.z + bb.z;
  float o3 = (v3 - mean) * rstd * gg.w + bb.w;
  u32 lo = (u32)f2bf(o0) | ((u32)f2bf(o1) << 16);
  u32 hi = (u32)f2bf(o2) | ((u32)f2bf(o3) << 16);
  uint2 st; st.x = lo; st.y = hi;
  *(uint2*)(xout + (size_t)tok * DD + tid * 4) = st;
}

// ---- K2: fused K+V projection, BK=64 (12 K-iters), grid (64,13); by==12 -> wq matvec ----
__global__ __launch_bounds__(256) void gemm_kv(const u16* __restrict__ A,
    const u16* __restrict__ wkT, const u16* __restrict__ wvT,
    const float* __restrict__ bkp, const float* __restrict__ bvp,
    u16* __restrict__ kb, u16* __restrict__ vb,
    const float* __restrict__ wqw, const int* __restrict__ gidx,
    float* __restrict__ qg) {
  __shared__ u16 As[128 * 64];   // 16 KB
  __shared__ u16 Bs[128 * 64];   // 16 KB
  __shared__ float s_in[4 * 64];
  int tid = threadIdx.x;
  if (blockIdx.y == 12) {
    // ---- wq 4-row matvec path (36 blocks; rest idle) ----
    if (blockIdx.x >= 36) return;
    int nc = blockIdx.x % 3, ky = blockIdx.x / 3;
    int rr = tid >> 6, kk0 = tid & 63;
    s_in[rr * 64 + kk0] = bf2f(A[(size_t)gidx[rr] * DD + ky * 64 + kk0]);
    __syncthreads();
    int n = nc * 256 + tid;
    int k0 = ky * 64;
    float a0 = 0.f, a1 = 0.f, a2 = 0.f, a3 = 0.f;
    for (int kk = 0; kk < 64; kk++) {
      float w = wqw[(size_t)(k0 + kk) * DD + n];
      a0 += s_in[kk] * w;
      a1 += s_in[64 + kk] * w;
      a2 += s_in[128 + kk] * w;
      a3 += s_in[192 + kk] * w;
    }
    atomicAdd(&qg[n], a0);
    atomicAdd(&qg[DD + n], a1);
    atomicAdd(&qg[2 * DD + n], a2);
    atomicAdd(&qg[3 * DD + n], a3);
    return;
  }
  const int K = DD, N = DD;
  int which = blockIdx.y >= 6;
  int m0 = blockIdx.x * 128;
  int n0 = (blockIdx.y - (which ? 6 : 0)) * 128;
  const u16* Bt = which ? wvT : wkT;
  const float* bias = which ? bvp : bkp;
  u16* C = which ? vb : kb;
  int lane = tid & 63, wave = tid >> 6;
  int wr = wave >> 1, wc = wave & 1;
  f32x4 acc[4][4] = {};
  // staging: 128x64 u16 tile = 1024 x 16B chunks; thread stages chunk q*256+tid, q=0..3
  const u16* ap[4]; const u16* bp[4];
  u16* AsW[4]; u16* BsW[4];
  #pragma unroll
  for (int q = 0; q < 4; q++) {
    int ch = q * 256 + tid;
    int rr = ch >> 3, su = ch & 7;
    ap[q] = A  + (size_t)(m0 + rr) * K + su * 8;
    bp[q] = Bt + (size_t)(n0 + rr) * K + su * 8;
    AsW[q] = As + (size_t)(q * 256 + wave * 64) * 8;
    BsW[q] = Bs + (size_t)(q * 256 + wave * 64) * 8;
  }
  int fr = lane & 15, fk = (lane >> 4) * 8;
  for (int k0 = 0; k0 < K; k0 += 64) {
    #pragma unroll
    for (int q = 0; q < 4; q++) {
      GLDS16(ap[q] + k0, AsW[q]);
      GLDS16(bp[q] + k0, BsW[q]);
    }
    __syncthreads();
    #pragma unroll
    for (int ks = 0; ks < 64; ks += 32) {
      bf16x8 af[4], bfr[4];
      #pragma unroll
      for (int i = 0; i < 4; i++)
        af[i] = *(const bf16x8*)(As + ((wr * 64 + i * 16 + fr) << 6) + ks + fk);
      #pragma unroll
      for (int j = 0; j < 4; j++)
        bfr[j] = *(const bf16x8*)(Bs + ((wc * 64 + j * 16 + fr) << 6) + ks + fk);
      #pragma unroll
      for (int i = 0; i < 4; i++)
        #pragma unroll
        for (int j = 0; j < 4; j++)
          acc[i][j] = __builtin_amdgcn_mfma_f32_16x16x32_bf16(af[i], bfr[j], acc[i][j], 0, 0, 0);
    }
    __syncthreads();
  }
  int cr = (lane >> 4) * 4;
  int cc = lane & 15;
  #pragma unroll
  for (int i = 0; i < 4; i++) {
    #pragma unroll
    for (int j = 0; j < 4; j++) {
      int col = n0 + wc * 64 + j * 16 + cc;
      float bvv = bias[col];
      int rowb = m0 + wr * 64 + i * 16 + cr;
      #pragma unroll
      for (int r = 0; r < 4; r++) {
        float v = acc[i][j][r] + bvv;
        C[(size_t)(rowb + r) * N + col] = f2bf(v);
      }
    }
  }
}

// ---- K3: global attention partial, both mention rows of a batch per block ----
__global__ __launch_bounds__(256) void gattn_part(const u16* __restrict__ kb,
    const u16* __restrict__ vb, const float* __restrict__ qg, const int* __restrict__ sent,
    float* __restrict__ part) {
  int sc = blockIdx.x, h = blockIdx.y, b = blockIdx.z;
  __shared__ float pbuf0[256], pbuf1[256];
  __shared__ float ovs0[32][64], ovs1[32][64];
  __shared__ float sbuf[8];
  int tid = threadIdx.x;
  int rsub = tid >> 3, csub = tid & 7;      // 32 row-groups x 8 d-chunks
  float qr0[8], qr1[8];
  #pragma unroll
  for (int j = 0; j < 8; j++) {
    qr0[j] = qg[(2 * b) * DD + h * 64 + csub * 8 + j];
    qr1[j] = qg[(2 * b + 1) * DD + h * 64 + csub * 8 + j];
  }
  size_t kbase = ((size_t)b * SS + sc * 256) * DD + h * 64 + csub * 8;
  #pragma unroll
  for (int pass = 0; pass < 8; pass++) {
    int rowi = pass * 32 + rsub;
    uint4 u = *(const uint4*)(kb + kbase + (size_t)rowi * DD);
    u32 vals[4] = {u.x, u.y, u.z, u.w};
    float d0 = 0.f, d1 = 0.f;
    #pragma unroll
    for (int t = 0; t < 4; t++) {
      float lo = __uint_as_float(vals[t] << 16);
      float hi = __uint_as_float(vals[t] & 0xFFFF0000u);
      d0 += qr0[t * 2] * lo + qr0[t * 2 + 1] * hi;
      d1 += qr1[t * 2] * lo + qr1[t * 2 + 1] * hi;
    }
    d0 += __shfl_xor(d0, 1, 64); d1 += __shfl_xor(d1, 1, 64);
    d0 += __shfl_xor(d0, 2, 64); d1 += __shfl_xor(d1, 2, 64);
    d0 += __shfl_xor(d0, 4, 64); d1 += __shfl_xor(d1, 4, 64);
    if (csub == 0) { pbuf0[rowi] = d0; pbuf1[rowi] = d1; }
  }
  __syncthreads();
  int ok = sent[b * SS + sc * 256 + tid] != 1;
  float s0 = ok ? pbuf0[tid] * 0.125f : -1e9f;
  float s1 = ok ? pbuf1[tid] * 0.125f : -1e9f;
  float m0 = blk_reduce<true>(s0, sbuf);
  float m1 = blk_reduce<true>(s1, sbuf);
  float p0 = expf(s0 - m0);
  float p1 = expf(s1 - m1);
  float ps0 = blk_reduce<false>(p0, sbuf);
  float ps1 = blk_reduce<false>(p1, sbuf);
  pbuf0[tid] = p0;
  pbuf1[tid] = p1;
  __syncthreads();
  float a0[8] = {0,0,0,0,0,0,0,0}, a1[8] = {0,0,0,0,0,0,0,0};
  #pragma unroll
  for (int pass = 0; pass < 8; pass++) {
    int rowi = pass * 32 + rsub;
    uint4 u = *(const uint4*)(vb + kbase + (size_t)rowi * DD);
    u32 vals[4] = {u.x, u.y, u.z, u.w};
    float pw0 = pbuf0[rowi], pw1 = pbuf1[rowi];
    #pragma unroll
    for (int t = 0; t < 4; t++) {
      float lo = __uint_as_float(vals[t] << 16);
      float hi = __uint_as_float(vals[t] & 0xFFFF0000u);
      a0[t * 2]     += pw0 * lo; a0[t * 2 + 1] += pw0 * hi;
      a1[t * 2]     += pw1 * lo; a1[t * 2 + 1] += pw1 * hi;
    }
  }
  #pragma unroll
  for (int j = 0; j < 8; j++) {
    ovs0[rsub][csub * 8 + j] = a0[j];
    ovs1[rsub][csub * 8 + j] = a1[j];
  }
  __syncthreads();
  float* pp0 = part + (((size_t)(2 * b) * HH + h) * 16 + sc) * 66;
  float* pp1 = part + (((size_t)(2 * b + 1) * HH + h) * 16 + sc) * 66;
  if (tid == 0) { pp0[0] = m0; pp0[1] = ps0; pp1[0] = m1; pp1[1] = ps1; }
  if (tid < 64) {
    float o0 = 0.f, o1 = 0.f;
    #pragma unroll
    for (int g2 = 0; g2 < 32; g2++) { o0 += ovs0[g2][tid]; o1 += ovs1[g2][tid]; }
    pp0[2 + tid] = o0;
    pp1[2 + tid] = o1;
  }
}

// ---- K4: wo matvec with fused softmax-combine (blockIdx.y == head) ----
__global__ __launch_bounds__(256) void matvec_wo(const float* __restrict__ W,
    const float* __restrict__ part, float* __restrict__ acc) {
  __shared__ float s_in[4][64];
  int h = blockIdx.y;
  int tid = threadIdx.x;
  int bg = tid >> 6, d = tid & 63;
  const float* pp = part + (((size_t)bg * HH + h) * 16) * 66;
  float M = -1e30f;
  for (int c = 0; c < 16; c++) M = fmaxf(M, pp[c * 66]);
  float Ssum = 0.f, o = 0.f;
  for (int c = 0; c < 16; c++) {
    float e = expf(pp[c * 66] - M);
    Ssum += pp[c * 66 + 1] * e;
    o += pp[c * 66 + 2 + d] * e;
  }
  s_in[bg][d] = o / Ssum;
  __syncthreads();
  int n = blockIdx.x * 256 + tid;
  int k0 = h * 64;
  float a0 = 0.f, a1 = 0.f, a2 = 0.f, a3 = 0.f;
  for (int kk = 0; kk < 64; kk++) {
    float w = W[(size_t)(k0 + kk) * DD + n];
    a0 += s_in[0][kk] * w;
    a1 += s_in[1][kk] * w;
    a2 += s_in[2][kk] * w;
    a3 += s_in[3][kk] * w;
  }
  atomicAdd(&acc[n], a0);
  atomicAdd(&acc[DD + n], a1);
  atomicAdd(&acc[2 * DD + n], a2);
  atomicAdd(&acc[3 * DD + n], a3);
}

// ---- K5: ln1 (recomputed per block) + w1 matvec. grid (12 n, 16 k-chunks of 48) ----
__global__ __launch_bounds__(256) void w1ln_k(const u16* __restrict__ xb,
    const int* __restrict__ gidx, const float* __restrict__ oacc,
    const float* __restrict__ g1, const float* __restrict__ be1,
    float* __restrict__ x1, const float* __restrict__ w1, float* __restrict__ f1a) {
  __shared__ float sbuf[8];
  __shared__ float xr[4][DD];
  int tid = threadIdx.x;
  for (int r = 0; r < 4; r++) {
    float v[3]; float sum = 0.f, sq = 0.f;
    #pragma unroll
    for (int i = 0; i < 3; i++) {
      int d = tid + i * 256;
      float t = bf2f(xb[(size_t)gidx[r] * DD + d]) + oacc[r * DD + d];
      v[i] = t; sum += t; sq += t * t;
    }
    sum = blk_reduce<false>(sum, sbuf);
    sq  = blk_reduce<false>(sq, sbuf);
    float mean = sum * (1.f / DD);
    float rstd = rsqrtf(sq * (1.f / DD) - mean * mean + 1e-5f);
    #pragma unroll
    for (int i = 0; i < 3; i++) {
      int d = tid + i * 256;
      xr[r][d] = (v[i] - mean) * rstd * g1[d] + be1[d];
    }
  }
  __syncthreads();
  if (blockIdx.x == 0 && blockIdx.y == 0) {
    for (int r = 0; r < 4; r++)
      #pragma unroll
      for (int i = 0; i < 3; i++) {
        int d = tid + i * 256;
        x1[r * DD + d] = xr[r][d];
      }
  }
  int k0 = blockIdx.y * 48;
  int n = blockIdx.x * 256 + tid;
  float a0 = 0.f, a1 = 0.f, a2 = 0.f, a3 = 0.f;
  for (int kk = 0; kk < 48; kk++) {
    float w = w1[(size_t)(k0 + kk) * FF + n];
    a0 += xr[0][k0 + kk] * w; a1 += xr[1][k0 + kk] * w;
    a2 += xr[2][k0 + kk] * w; a3 += xr[3][k0 + kk] * w;
  }
  atomicAdd(&f1a[n], a0);
  atomicAdd(&f1a[FF + n], a1);
  atomicAdd(&f1a[2 * FF + n], a2);
  atomicAdd(&f1a[3 * FF + n], a3);
}

// ---- K6: gelu + w2 matvec. grid (3 n, 64 k-chunks of 48) ----
__global__ __launch_bounds__(256) void w2_k(const float* __restrict__ f1a,
    const float* __restrict__ w2, float* __restrict__ f2a) {
  __shared__ float sI[4][48];
  int tid = threadIdx.x;
  int k0 = blockIdx.y * 48;
  for (int idx = tid; idx < 192; idx += 256) {
    int r = idx / 48, kk = idx % 48;
    sI[r][kk] = gelu_f(f1a[(size_t)r * FF + k0 + kk]);
  }
  __syncthreads();
  int n = blockIdx.x * 256 + tid;
  float a0 = 0.f, a1 = 0.f, a2 = 0.f, a3 = 0.f;
  for (int kk = 0; kk < 48; kk++) {
    float w = w2[(size_t)(k0 + kk) * DD + n];
    a0 += sI[0][kk] * w; a1 += sI[1][kk] * w;
    a2 += sI[2][kk] * w; a3 += sI[3][kk] * w;
  }
  atomicAdd(&f2a[n], a0);
  atomicAdd(&f2a[DD + n], a1);
  atomicAdd(&f2a[2 * DD + n], a2);
  atomicAdd(&f2a[3 * DD + n], a3);
}

// ---- K7: ln2 (recomputed per block) + logits. 128 blocks ----
__global__ __launch_bounds__(256) void logits_k(const float* __restrict__ x1,
    const float* __restrict__ f2a, const float* __restrict__ g2,
    const float* __restrict__ be2, const float* __restrict__ ex,
    float* __restrict__ out) {
  __shared__ float sbuf[8];
  __shared__ float hw[4][DD];
  int tid = threadIdx.x;
  for (int r = 0; r < 4; r++) {
    float v[3]; float sum = 0.f, sq = 0.f;
    #pragma unroll
    for (int i = 0; i < 3; i++) {
      int d = tid + i * 256;
      float t = x1[r * DD + d] + f2a[r * DD + d];
      v[i] = t; sum += t; sq += t * t;
    }
    sum = blk_reduce<false>(sum, sbuf);
    sq  = blk_reduce<false>(sq, sbuf);
    float mean = sum * (1.f / DD);
    float rstd = rsqrtf(sq * (1.f / DD) - mean * mean + 1e-5f);
    #pragma unroll
    for (int i = 0; i < 3; i++) {
      int d = tid + i * 256;
      hw[r][d] = (v[i] - mean) * rstd * g2[d] + be2[d];
    }
  }
  __syncthreads();
  int j = blockIdx.x;
  const float* er = ex + (size_t)j * 1536;
  float d0 = 0.f, d1 = 0.f;
  for (int c = tid; c < DD; c += 256) {
    float e0 = er[c], e1 = er[DD + c];
    d0 += hw[0][c] * e0 + hw[1][c] * e1;
    d1 += hw[2][c] * e0 + hw[3][c] * e1;
  }
  d0 = blk_reduce<false>(d0, sbuf);
  d1 = blk_reduce<false>(d1, sbuf);
  if (tid == 0) { out[j] = d0; out[128 + j] = d1; }
}

// ---- K8: loss ----
__global__ __launch_bounds__(128) void loss_k(const float* __restrict__ lg,
    const int* __restrict__ labels, float* __restrict__ out) {
  __shared__ float sbuf[8];
  int tid = threadIdx.x;
  float v0 = lg[tid], v1 = lg[128 + tid];
  float m0 = blk_reduce<true>(v0, sbuf);
  float m1 = blk_reduce<true>(v1, sbuf);
  float s0 = blk_reduce<false>(expf(v0 - m0), sbuf);
  float s1 = blk_reduce<false>(expf(v1 - m1), sbuf);
  if (tid == 0) {
    float lp0 = lg[labels[0]] - m0 - logf(s0);
    float lp1 = lg[128 + labels[1]] - m1 - logf(s1);
    out[256] = -(lp0 + lp1);
  }
}

extern "C" void kernel_launch(void* const* d_in, const int* in_sizes, int n_in,
                              void* d_out, int out_size, void* d_ws, size_t ws_size,
                              hipStream_t stream) {
  const int*   sent = (const int*)d_in[0];
  const int*   sp   = (const int*)d_in[1];
  const int*   ep   = (const int*)d_in[2];
  const int*   lab  = (const int*)d_in[3];
  const float* emb  = (const float*)d_in[4];
  const float* pos  = (const float*)d_in[5];
  const float* ln0g = (const float*)d_in[6];
  const float* ln0b = (const float*)d_in[7];
  const float* wq   = (const float*)d_in[8];
  const float* bq   = (const float*)d_in[9];
  const float* wk   = (const float*)d_in[10];
  const float* bk   = (const float*)d_in[11];
  const float* wv   = (const float*)d_in[12];
  const float* bv   = (const float*)d_in[13];
  const float* wo   = (const float*)d_in[14];
  const float* bo   = (const float*)d_in[15];
  const float* ln1g = (const float*)d_in[16];
  const float* ln1b = (const float*)d_in[17];
  const float* w1   = (const float*)d_in[18];
  const float* b1   = (const float*)d_in[19];
  const float* w2   = (const float*)d_in[20];
  const float* b2   = (const float*)d_in[21];
  const float* ln2g = (const float*)d_in[22];
  const float* ln2b = (const float*)d_in[23];
  const float* ex   = (const float*)d_in[24];
  float* out = (float*)d_out;

  char* basep = (char*)d_ws;
  size_t off = 0;
  auto alloc = [&](size_t bytes) -> void* {
    void* p = basep + off;
    off = (off + bytes + 255) & ~(size_t)255;
    return p;
  };
  u16*   xb   = (u16*)alloc((size_t)NTOK * DD * 2);
  u16*   kb   = (u16*)alloc((size_t)NTOK * DD * 2);
  u16*   vb   = (u16*)alloc((size_t)NTOK * DD * 2);
  u16*   wkT  = (u16*)alloc((size_t)DD * DD * 2);
  u16*   wvT  = (u16*)alloc((size_t)DD * DD * 2);
  float* qg   = (float*)alloc(4 * DD * 4);
  float* oacc = (float*)alloc(4 * DD * 4);
  float* x1   = (float*)alloc(4 * DD * 4);
  float* f1a  = (float*)alloc(4 * FF * 4);
  float* f2a  = (float*)alloc(4 * DD * 4);
  float* part = (float*)alloc((size_t)4 * HH * 16 * 66 * 4);
  int*   gidx = (int*)alloc(64);

  embed_ln_k<<<NTOK + 1152, 192, 0, stream>>>(sent, emb, pos, ln0g, ln0b, xb,
      wk, wv, wkT, wvT, sp, ep, bq, bo, b1, b2, qg, oacc, f1a, f2a, gidx);
  gemm_kv<<<dim3(64, 13), 256, 0, stream>>>(xb, wkT, wvT, bk, bv, kb, vb, wq, gidx, qg);
  gattn_part<<<dim3(16, HH, 2), 256, 0, stream>>>(kb, vb, qg, sent, part);
  matvec_wo<<<dim3(3, HH), 256, 0, stream>>>(wo, part, oacc);
  w1ln_k<<<dim3(12, 16), 256, 0, stream>>>(xb, gidx, oacc, ln1g, ln1b, x1, w1, f1a);
  w2_k<<<dim3(3, 64), 256, 0, stream>>>(f1a, w2, f2a);
  logits_k<<<128, 256, 0, stream>>>(x1, f2a, ln2g, ln2b, ex, out);
  loss_k<<<1, 128, 0, stream>>>(out, lab, out);
}

// Round 10
// 107.161 us; speedup vs baseline: 1.0155x; 1.0155x over previous
//
#include <hip/hip_runtime.h>

typedef unsigned short u16;
typedef unsigned int   u32;
typedef __attribute__((ext_vector_type(8))) short bf16x8;
typedef __attribute__((ext_vector_type(4))) float f32x4;

#define BB 2
#define SS 4096
#define DD 768
#define HH 12
#define FF 3072
#define NTOK 8192

#define GLDS16(gp, lp) __builtin_amdgcn_global_load_lds(                      \
    (const __attribute__((address_space(1))) u32*)(gp),                       \
    (__attribute__((address_space(3))) u32*)(lp), 16, 0, 0)

__device__ __forceinline__ float bf2f(u16 u) {
  return __uint_as_float(((u32)u) << 16);
}
__device__ __forceinline__ u16 f2bf(float f) {
  u32 x = __float_as_uint(f);
  x = x + 0x7FFFu + ((x >> 16) & 1u);
  return (u16)(x >> 16);
}
__device__ __forceinline__ float gelu_f(float v) {
  return 0.5f * v * (1.0f + erff(v * 0.70710678118654752f));
}

template<bool MAXOP>
__device__ __forceinline__ float blk_reduce(float v, float* sbuf) {
  #pragma unroll
  for (int o = 32; o > 0; o >>= 1) {
    float t = __shfl_xor(v, o, 64);
    v = MAXOP ? fmaxf(v, t) : (v + t);
  }
  int wave = threadIdx.x >> 6;
  int nw = blockDim.x >> 6;
  __syncthreads();
  if ((threadIdx.x & 63) == 0) sbuf[wave] = v;
  __syncthreads();
  float r = sbuf[0];
  for (int i = 1; i < nw; i++) r = MAXOP ? fmaxf(r, sbuf[i]) : (r + sbuf[i]);
  return r;
}

// ---- K1: transpose+cvt wk,wv (grid z=0,1) + seed (block 0,0,0 extra work) ----
__global__ __launch_bounds__(256) void transcvt2(const float* __restrict__ wk,
    const float* __restrict__ wv, u16* __restrict__ wkT, u16* __restrict__ wvT,
    const int* sp, const int* ep, const float* bq, const float* bo,
    const float* b1, const float* b2,
    float* qg, float* oa, float* f1, float* f2, int* gidx) {
  int tid = threadIdx.x;
  if (blockIdx.x == 0 && blockIdx.y == 0 && blockIdx.z == 0) {
    if (tid < 4) {
      int b = tid >> 1;
      int s = (tid & 1) ? ep[b] : sp[b];
      gidx[tid] = b * SS + s;
    }
    for (int i = tid; i < DD; i += 256) {
      float vq = bq[i], vo = bo[i], v2 = b2[i];
      #pragma unroll
      for (int r = 0; r < 4; r++) {
        qg[r * DD + i] = vq; oa[r * DD + i] = vo; f2[r * DD + i] = v2;
      }
    }
    for (int i = tid; i < FF; i += 256) {
      float v1 = b1[i];
      #pragma unroll
      for (int r = 0; r < 4; r++) f1[r * FF + i] = v1;
    }
  }
  const float* W = blockIdx.z ? wv : wk;
  u16* WT = blockIdx.z ? wvT : wkT;
  __shared__ float t[32][33];
  int n0 = blockIdx.x * 32, k0 = blockIdx.y * 32;
  int tx = tid & 31, ty = tid >> 5; // 32x8
  #pragma unroll
  for (int i = 0; i < 32; i += 8)
    t[ty + i][tx] = W[(size_t)(k0 + ty + i) * DD + n0 + tx];
  __syncthreads();
  #pragma unroll
  for (int i = 0; i < 32; i += 8)
    WT[(size_t)(n0 + ty + i) * DD + k0 + tx] = f2bf(t[tx][ty + i]);
}

// ---- K2: x = LN(emb[sent] + pos) -> bf16, one block per token, float4 loads ----
__global__ __launch_bounds__(192) void embed_ln_k(const int* __restrict__ sent,
    const float* __restrict__ emb, const float* __restrict__ pos,
    const float* __restrict__ g, const float* __restrict__ be, u16* __restrict__ xout) {
  __shared__ float sbuf[8];
  int tok = blockIdx.x;
  int s = tok & (SS - 1);
  int row = sent[tok];
  int tid = threadIdx.x;
  float4 e = *(const float4*)(emb + (size_t)row * DD + tid * 4);
  float4 p = *(const float4*)(pos + (size_t)s * DD + tid * 4);
  float v0 = e.x + p.x, v1 = e.y + p.y, v2 = e.z + p.z, v3 = e.w + p.w;
  float sum = v0 + v1 + v2 + v3;
  float sq  = v0 * v0 + v1 * v1 + v2 * v2 + v3 * v3;
  sum = blk_reduce<false>(sum, sbuf);
  sq  = blk_reduce<false>(sq, sbuf);
  float mean = sum * (1.f / DD);
  float var  = sq * (1.f / DD) - mean * mean;
  float rstd = rsqrtf(var + 1e-5f);
  float4 gg = *(const float4*)(g + tid * 4);
  float4 bb = *(const float4*)(be + tid * 4);
  float o0 = (v0 - mean) * rstd * gg.x + bb.x;
  float o1 = (v1 - mean) * rstd * gg.y + bb.y;
  float o2 = (v2 - mean) * rstd * gg.z + bb.z;
  float o3 = (v3 - mean) * rstd * gg.w + bb.w;
  u32 lo = (u32)f2bf(o0) | ((u32)f2bf(o1) << 16);
  u32 hi = (u32)f2bf(o2) | ((u32)f2bf(o3) << 16);
  uint2 st; st.x = lo; st.y = hi;
  *(uint2*)(xout + (size_t)tok * DD + tid * 4) = st;
}

// ---- K3: fused K+V projection (m97-style, BK=32), 1D grid 804, XCD-chunked swizzle.
//      wgid<768: GEMM (m=wgid/12, t=wgid%12; t<6 -> K, else V). wgid>=768: wq matvec. ----
__global__ __launch_bounds__(256) void gemm_kv(const u16* __restrict__ A,
    const u16* __restrict__ wkT, const u16* __restrict__ wvT,
    const float* __restrict__ bkp, const float* __restrict__ bvp,
    u16* __restrict__ kb, u16* __restrict__ vb,
    const float* __restrict__ wqw, const int* __restrict__ gidx,
    float* __restrict__ qg) {
  __shared__ u16 As[128 * 32];
  __shared__ u16 Bs[128 * 32];
  __shared__ float s_in[4 * 64];
  int tid = threadIdx.x;
  // bijective XCD-chunked swizzle (m204): nwg=804, q=100, r=4
  int orig = blockIdx.x;
  int xcd = orig & 7, cidx = orig >> 3;
  int wgid = (xcd < 4 ? xcd * 101 : 404 + (xcd - 4) * 100) + cidx;
  if (wgid >= 768) {
    // ---- wq 4-row matvec path (36 blocks; rest idle) ----
    int wqi = wgid - 768;
    if (wqi >= 36) return;
    int nc = wqi % 3, ky = wqi / 3;
    int rr = tid >> 6, kk0 = tid & 63;
    s_in[rr * 64 + kk0] = bf2f(A[(size_t)gidx[rr] * DD + ky * 64 + kk0]);
    __syncthreads();
    int n = nc * 256 + tid;
    int k0 = ky * 64;
    float a0 = 0.f, a1 = 0.f, a2 = 0.f, a3 = 0.f;
    for (int kk = 0; kk < 64; kk++) {
      float w = wqw[(size_t)(k0 + kk) * DD + n];
      a0 += s_in[kk] * w;
      a1 += s_in[64 + kk] * w;
      a2 += s_in[128 + kk] * w;
      a3 += s_in[192 + kk] * w;
    }
    atomicAdd(&qg[n], a0);
    atomicAdd(&qg[DD + n], a1);
    atomicAdd(&qg[2 * DD + n], a2);
    atomicAdd(&qg[3 * DD + n], a3);
    return;
  }
  const int K = DD, N = DD;
  int mx = wgid / 12, t = wgid % 12;
  int which = t >= 6;
  int m0 = mx * 128;
  int n0 = (t - (which ? 6 : 0)) * 128;
  const u16* Bt = which ? wvT : wkT;
  const float* bias = which ? bvp : bkp;
  u16* C = which ? vb : kb;
  int lane = tid & 63, wave = tid >> 6;
  int wr = wave >> 1, wc = wave & 1;
  f32x4 acc[4][4] = {};
  int ch0 = wave * 64 + lane;
  int r0 = ch0 >> 2, su0 = ch0 & 3;
  int ch1 = 256 + ch0;
  int r1 = ch1 >> 2, su1 = ch1 & 3;
  const u16* a0p = A  + (size_t)(m0 + r0) * K + su0 * 8;
  const u16* a1p = A  + (size_t)(m0 + r1) * K + su1 * 8;
  const u16* b0p = Bt + (size_t)(n0 + r0) * K + su0 * 8;
  const u16* b1p = Bt + (size_t)(n0 + r1) * K + su1 * 8;
  u16* AsW0 = As + (size_t)(wave * 64) * 8;
  u16* AsW1 = As + (size_t)(256 + wave * 64) * 8;
  u16* BsW0 = Bs + (size_t)(wave * 64) * 8;
  u16* BsW1 = Bs + (size_t)(256 + wave * 64) * 8;
  int fr = lane & 15, fk = (lane >> 4) * 8;
  for (int k0 = 0; k0 < K; k0 += 32) {
    GLDS16(a0p + k0, AsW0);
    GLDS16(a1p + k0, AsW1);
    GLDS16(b0p + k0, BsW0);
    GLDS16(b1p + k0, BsW1);
    __syncthreads();
    bf16x8 af[4], bfr[4];
    #pragma unroll
    for (int i = 0; i < 4; i++)
      af[i] = *(const bf16x8*)(As + ((wr * 64 + i * 16 + fr) << 5) + fk);
    #pragma unroll
    for (int j = 0; j < 4; j++)
      bfr[j] = *(const bf16x8*)(Bs + ((wc * 64 + j * 16 + fr) << 5) + fk);
    #pragma unroll
    for (int i = 0; i < 4; i++)
      #pragma unroll
      for (int j = 0; j < 4; j++)
        acc[i][j] = __builtin_amdgcn_mfma_f32_16x16x32_bf16(af[i], bfr[j], acc[i][j], 0, 0, 0);
    __syncthreads();
  }
  int cr = (lane >> 4) * 4;
  int cc = lane & 15;
  #pragma unroll
  for (int i = 0; i < 4; i++) {
    #pragma unroll
    for (int j = 0; j < 4; j++) {
      int col = n0 + wc * 64 + j * 16 + cc;
      float bvv = bias[col];
      int rowb = m0 + wr * 64 + i * 16 + cr;
      #pragma unroll
      for (int r = 0; r < 4; r++) {
        float v = acc[i][j][r] + bvv;
        C[(size_t)(rowb + r) * N + col] = f2bf(v);
      }
    }
  }
}

// ---- K4: global attention partial, both mention rows of a batch per block ----
__global__ __launch_bounds__(256) void gattn_part(const u16* __restrict__ kb,
    const u16* __restrict__ vb, const float* __restrict__ qg, const int* __restrict__ sent,
    float* __restrict__ part) {
  int sc = blockIdx.x, h = blockIdx.y, b = blockIdx.z;
  __shared__ float pbuf0[256], pbuf1[256];
  __shared__ float ovs0[32][64], ovs1[32][64];
  __shared__ float sbuf[8];
  int tid = threadIdx.x;
  int rsub = tid >> 3, csub = tid & 7;      // 32 row-groups x 8 d-chunks
  float qr0[8], qr1[8];
  #pragma unroll
  for (int j = 0; j < 8; j++) {
    qr0[j] = qg[(2 * b) * DD + h * 64 + csub * 8 + j];
    qr1[j] = qg[(2 * b + 1) * DD + h * 64 + csub * 8 + j];
  }
  size_t kbase = ((size_t)b * SS + sc * 256) * DD + h * 64 + csub * 8;
  #pragma unroll
  for (int pass = 0; pass < 8; pass++) {
    int rowi = pass * 32 + rsub;
    uint4 u = *(const uint4*)(kb + kbase + (size_t)rowi * DD);
    u32 vals[4] = {u.x, u.y, u.z, u.w};
    float d0 = 0.f, d1 = 0.f;
    #pragma unroll
    for (int t = 0; t < 4; t++) {
      float lo = __uint_as_float(vals[t] << 16);
      float hi = __uint_as_float(vals[t] & 0xFFFF0000u);
      d0 += qr0[t * 2] * lo + qr0[t * 2 + 1] * hi;
      d1 += qr1[t * 2] * lo + qr1[t * 2 + 1] * hi;
    }
    d0 += __shfl_xor(d0, 1, 64); d1 += __shfl_xor(d1, 1, 64);
    d0 += __shfl_xor(d0, 2, 64); d1 += __shfl_xor(d1, 2, 64);
    d0 += __shfl_xor(d0, 4, 64); d1 += __shfl_xor(d1, 4, 64);
    if (csub == 0) { pbuf0[rowi] = d0; pbuf1[rowi] = d1; }
  }
  __syncthreads();
  int ok = sent[b * SS + sc * 256 + tid] != 1;
  float s0 = ok ? pbuf0[tid] * 0.125f : -1e9f;
  float s1 = ok ? pbuf1[tid] * 0.125f : -1e9f;
  float m0 = blk_reduce<true>(s0, sbuf);
  float m1 = blk_reduce<true>(s1, sbuf);
  float p0 = expf(s0 - m0);
  float p1 = expf(s1 - m1);
  float ps0 = blk_reduce<false>(p0, sbuf);
  float ps1 = blk_reduce<false>(p1, sbuf);
  pbuf0[tid] = p0;
  pbuf1[tid] = p1;
  __syncthreads();
  float a0[8] = {0,0,0,0,0,0,0,0}, a1[8] = {0,0,0,0,0,0,0,0};
  #pragma unroll
  for (int pass = 0; pass < 8; pass++) {
    int rowi = pass * 32 + rsub;
    uint4 u = *(const uint4*)(vb + kbase + (size_t)rowi * DD);
    u32 vals[4] = {u.x, u.y, u.z, u.w};
    float pw0 = pbuf0[rowi], pw1 = pbuf1[rowi];
    #pragma unroll
    for (int t = 0; t < 4; t++) {
      float lo = __uint_as_float(vals[t] << 16);
      float hi = __uint_as_float(vals[t] & 0xFFFF0000u);
      a0[t * 2]     += pw0 * lo; a0[t * 2 + 1] += pw0 * hi;
      a1[t * 2]     += pw1 * lo; a1[t * 2 + 1] += pw1 * hi;
    }
  }
  #pragma unroll
  for (int j = 0; j < 8; j++) {
    ovs0[rsub][csub * 8 + j] = a0[j];
    ovs1[rsub][csub * 8 + j] = a1[j];
  }
  __syncthreads();
  float* pp0 = part + (((size_t)(2 * b) * HH + h) * 16 + sc) * 66;
  float* pp1 = part + (((size_t)(2 * b + 1) * HH + h) * 16 + sc) * 66;
  if (tid == 0) { pp0[0] = m0; pp0[1] = ps0; pp1[0] = m1; pp1[1] = ps1; }
  if (tid < 64) {
    float o0 = 0.f, o1 = 0.f;
    #pragma unroll
    for (int g2 = 0; g2 < 32; g2++) { o0 += ovs0[g2][tid]; o1 += ovs1[g2][tid]; }
    pp0[2 + tid] = o0;
    pp1[2 + tid] = o1;
  }
}

// ---- K5: wo matvec with fused softmax-combine (blockIdx.y == head) ----
__global__ __launch_bounds__(256) void matvec_wo(const float* __restrict__ W,
    const float* __restrict__ part, float* __restrict__ acc) {
  __shared__ float s_in[4][64];
  int h = blockIdx.y;
  int tid = threadIdx.x;
  int bg = tid >> 6, d = tid & 63;
  const float* pp = part + (((size_t)bg * HH + h) * 16) * 66;
  float M = -1e30f;
  for (int c = 0; c < 16; c++) M = fmaxf(M, pp[c * 66]);
  float Ssum = 0.f, o = 0.f;
  for (int c = 0; c < 16; c++) {
    float e = expf(pp[c * 66] - M);
    Ssum += pp[c * 66 + 1] * e;
    o += pp[c * 66 + 2 + d] * e;
  }
  s_in[bg][d] = o / Ssum;
  __syncthreads();
  int n = blockIdx.x * 256 + tid;
  int k0 = h * 64;
  float a0 = 0.f, a1 = 0.f, a2 = 0.f, a3 = 0.f;
  for (int kk = 0; kk < 64; kk++) {
    float w = W[(size_t)(k0 + kk) * DD + n];
    a0 += s_in[0][kk] * w;
    a1 += s_in[1][kk] * w;
    a2 += s_in[2][kk] * w;
    a3 += s_in[3][kk] * w;
  }
  atomicAdd(&acc[n], a0);
  atomicAdd(&acc[DD + n], a1);
  atomicAdd(&acc[2 * DD + n], a2);
  atomicAdd(&acc[3 * DD + n], a3);
}

// ---- K6: ln1 (recomputed per block) + w1 matvec. grid (12 n, 16 k-chunks of 48) ----
__global__ __launch_bounds__(256) void w1ln_k(const u16* __restrict__ xb,
    const int* __restrict__ gidx, const float* __restrict__ oacc,
    const float* __restrict__ g1, const float* __restrict__ be1,
    float* __restrict__ x1, const float* __restrict__ w1, float* __restrict__ f1a) {
  __shared__ float sbuf[8];
  __shared__ float xr[4][DD];
  int tid = threadIdx.x;
  for (int r = 0; r < 4; r++) {
    float v[3]; float sum = 0.f, sq = 0.f;
    #pragma unroll
    for (int i = 0; i < 3; i++) {
      int d = tid + i * 256;
      float t = bf2f(xb[(size_t)gidx[r] * DD + d]) + oacc[r * DD + d];
      v[i] = t; sum += t; sq += t * t;
    }
    sum = blk_reduce<false>(sum, sbuf);
    sq  = blk_reduce<false>(sq, sbuf);
    float mean = sum * (1.f / DD);
    float rstd = rsqrtf(sq * (1.f / DD) - mean * mean + 1e-5f);
    #pragma unroll
    for (int i = 0; i < 3; i++) {
      int d = tid + i * 256;
      xr[r][d] = (v[i] - mean) * rstd * g1[d] + be1[d];
    }
  }
  __syncthreads();
  if (blockIdx.x == 0 && blockIdx.y == 0) {
    for (int r = 0; r < 4; r++)
      #pragma unroll
      for (int i = 0; i < 3; i++) {
        int d = tid + i * 256;
        x1[r * DD + d] = xr[r][d];
      }
  }
  int k0 = blockIdx.y * 48;
  int n = blockIdx.x * 256 + tid;
  float a0 = 0.f, a1 = 0.f, a2 = 0.f, a3 = 0.f;
  for (int kk = 0; kk < 48; kk++) {
    float w = w1[(size_t)(k0 + kk) * FF + n];
    a0 += xr[0][k0 + kk] * w; a1 += xr[1][k0 + kk] * w;
    a2 += xr[2][k0 + kk] * w; a3 += xr[3][k0 + kk] * w;
  }
  atomicAdd(&f1a[n], a0);
  atomicAdd(&f1a[FF + n], a1);
  atomicAdd(&f1a[2 * FF + n], a2);
  atomicAdd(&f1a[3 * FF + n], a3);
}

// ---- K7: gelu + w2 matvec. grid (3 n, 64 k-chunks of 48) ----
__global__ __launch_bounds__(256) void w2_k(const float* __restrict__ f1a,
    const float* __restrict__ w2, float* __restrict__ f2a) {
  __shared__ float sI[4][48];
  int tid = threadIdx.x;
  int k0 = blockIdx.y * 48;
  for (int idx = tid; idx < 192; idx += 256) {
    int r = idx / 48, kk = idx % 48;
    sI[r][kk] = gelu_f(f1a[(size_t)r * FF + k0 + kk]);
  }
  __syncthreads();
  int n = blockIdx.x * 256 + tid;
  float a0 = 0.f, a1 = 0.f, a2 = 0.f, a3 = 0.f;
  for (int kk = 0; kk < 48; kk++) {
    float w = w2[(size_t)(k0 + kk) * DD + n];
    a0 += sI[0][kk] * w; a1 += sI[1][kk] * w;
    a2 += sI[2][kk] * w; a3 += sI[3][kk] * w;
  }
  atomicAdd(&f2a[n], a0);
  atomicAdd(&f2a[DD + n], a1);
  atomicAdd(&f2a[2 * DD + n], a2);
  atomicAdd(&f2a[3 * DD + n], a3);
}

// ---- K8: ln2 (recomputed per block) + logits. 128 blocks ----
__global__ __launch_bounds__(256) void logits_k(const float* __restrict__ x1,
    const float* __restrict__ f2a, const float* __restrict__ g2,
    const float* __restrict__ be2, const float* __restrict__ ex,
    float* __restrict__ out) {
  __shared__ float sbuf[8];
  __shared__ float hw[4][DD];
  int tid = threadIdx.x;
  for (int r = 0; r < 4; r++) {
    float v[3]; float sum = 0.f, sq = 0.f;
    #pragma unroll
    for (int i = 0; i < 3; i++) {
      int d = tid + i * 256;
      float t = x1[r * DD + d] + f2a[r * DD + d];
      v[i] = t; sum += t; sq += t * t;
    }
    sum = blk_reduce<false>(sum, sbuf);
    sq  = blk_reduce<false>(sq, sbuf);
    float mean = sum * (1.f / DD);
    float rstd = rsqrtf(sq * (1.f / DD) - mean * mean + 1e-5f);
    #pragma unroll
    for (int i = 0; i < 3; i++) {
      int d = tid + i * 256;
      hw[r][d] = (v[i] - mean) * rstd * g2[d] + be2[d];
    }
  }
  __syncthreads();
  int j = blockIdx.x;
  const float* er = ex + (size_t)j * 1536;
  float d0 = 0.f, d1 = 0.f;
  for (int c = tid; c < DD; c += 256) {
    float e0 = er[c], e1 = er[DD + c];
    d0 += hw[0][c] * e0 + hw[1][c] * e1;
    d1 += hw[2][c] * e0 + hw[3][c] * e1;
  }
  d0 = blk_reduce<false>(d0, sbuf);
  d1 = blk_reduce<false>(d1, sbuf);
  if (tid == 0) { out[j] = d0; out[128 + j] = d1; }
}

// ---- K9: loss ----
__global__ __launch_bounds__(128) void loss_k(const float* __restrict__ lg,
    const int* __restrict__ labels, float* __restrict__ out) {
  __shared__ float sbuf[8];
  int tid = threadIdx.x;
  float v0 = lg[tid], v1 = lg[128 + tid];
  float m0 = blk_reduce<true>(v0, sbuf);
  float m1 = blk_reduce<true>(v1, sbuf);
  float s0 = blk_reduce<false>(expf(v0 - m0), sbuf);
  float s1 = blk_reduce<false>(expf(v1 - m1), sbuf);
  if (tid == 0) {
    float lp0 = lg[labels[0]] - m0 - logf(s0);
    float lp1 = lg[128 + labels[1]] - m1 - logf(s1);
    out[256] = -(lp0 + lp1);
  }
}

extern "C" void kernel_launch(void* const* d_in, const int* in_sizes, int n_in,
                              void* d_out, int out_size, void* d_ws, size_t ws_size,
                              hipStream_t stream) {
  const int*   sent = (const int*)d_in[0];
  const int*   sp   = (const int*)d_in[1];
  const int*   ep   = (const int*)d_in[2];
  const int*   lab  = (const int*)d_in[3];
  const float* emb  = (const float*)d_in[4];
  const float* pos  = (const float*)d_in[5];
  const float* ln0g = (const float*)d_in[6];
  const float* ln0b = (const float*)d_in[7];
  const float* wq   = (const float*)d_in[8];
  const float* bq   = (const float*)d_in[9];
  const float* wk   = (const float*)d_in[10];
  const float* bk   = (const float*)d_in[11];
  const float* wv   = (const float*)d_in[12];
  const float* bv   = (const float*)d_in[13];
  const float* wo   = (const float*)d_in[14];
  const float* bo   = (const float*)d_in[15];
  const float* ln1g = (const float*)d_in[16];
  const float* ln1b = (const float*)d_in[17];
  const float* w1   = (const float*)d_in[18];
  const float* b1   = (const float*)d_in[19];
  const float* w2   = (const float*)d_in[20];
  const float* b2   = (const float*)d_in[21];
  const float* ln2g = (const float*)d_in[22];
  const float* ln2b = (const float*)d_in[23];
  const float* ex   = (const float*)d_in[24];
  float* out = (float*)d_out;

  char* basep = (char*)d_ws;
  size_t off = 0;
  auto alloc = [&](size_t bytes) -> void* {
    void* p = basep + off;
    off = (off + bytes + 255) & ~(size_t)255;
    return p;
  };
  u16*   xb   = (u16*)alloc((size_t)NTOK * DD * 2);
  u16*   kb   = (u16*)alloc((size_t)NTOK * DD * 2);
  u16*   vb   = (u16*)alloc((size_t)NTOK * DD * 2);
  u16*   wkT  = (u16*)alloc((size_t)DD * DD * 2);
  u16*   wvT  = (u16*)alloc((size_t)DD * DD * 2);
  float* qg   = (float*)alloc(4 * DD * 4);
  float* oacc = (float*)alloc(4 * DD * 4);
  float* x1   = (float*)alloc(4 * DD * 4);
  float* f1a  = (float*)alloc(4 * FF * 4);
  float* f2a  = (float*)alloc(4 * DD * 4);
  float* part = (float*)alloc((size_t)4 * HH * 16 * 66 * 4);
  int*   gidx = (int*)alloc(64);

  transcvt2<<<dim3(24, 24, 2), 256, 0, stream>>>(wk, wv, wkT, wvT,
      sp, ep, bq, bo, b1, b2, qg, oacc, f1a, f2a, gidx);
  embed_ln_k<<<NTOK, 192, 0, stream>>>(sent, emb, pos, ln0g, ln0b, xb);
  gemm_kv<<<804, 256, 0, stream>>>(xb, wkT, wvT, bk, bv, kb, vb, wq, gidx, qg);
  gattn_part<<<dim3(16, HH, 2), 256, 0, stream>>>(kb, vb, qg, sent, part);
  matvec_wo<<<dim3(3, HH), 256, 0, stream>>>(wo, part, oacc);
  w1ln_k<<<dim3(12, 16), 256, 0, stream>>>(xb, gidx, oacc, ln1g, ln1b, x1, w1, f1a);
  w2_k<<<dim3(3, 64), 256, 0, stream>>>(f1a, w2, f2a);
  logits_k<<<128, 256, 0, stream>>>(x1, f2a, ln2g, ln2b, ex, out);
  loss_k<<<1, 128, 0, stream>>>(out, lab, out);
}

// Round 11
// 105.226 us; speedup vs baseline: 1.0342x; 1.0184x over previous
//
#include <hip/hip_runtime.h>

typedef unsigned short u16;
typedef unsigned int   u32;
typedef __attribute__((ext_vector_type(8))) short bf16x8;
typedef __attribute__((ext_vector_type(4))) float f32x4;

#define BB 2
#define SS 4096
#define DD 768
#define HH 12
#define FF 3072
#define NTOK 8192

#define GLDS16(gp, lp) __builtin_amdgcn_global_load_lds(                      \
    (const __attribute__((address_space(1))) u32*)(gp),                       \
    (__attribute__((address_space(3))) u32*)(lp), 16, 0, 0)

__device__ __forceinline__ float bf2f(u16 u) {
  return __uint_as_float(((u32)u) << 16);
}
__device__ __forceinline__ u16 f2bf(float f) {
  u32 x = __float_as_uint(f);
  x = x + 0x7FFFu + ((x >> 16) & 1u);
  return (u16)(x >> 16);
}
__device__ __forceinline__ float gelu_f(float v) {
  return 0.5f * v * (1.0f + erff(v * 0.70710678118654752f));
}

template<bool MAXOP>
__device__ __forceinline__ float blk_reduce(float v, float* sbuf) {
  #pragma unroll
  for (int o = 32; o > 0; o >>= 1) {
    float t = __shfl_xor(v, o, 64);
    v = MAXOP ? fmaxf(v, t) : (v + t);
  }
  int wave = threadIdx.x >> 6;
  int nw = blockDim.x >> 6;
  __syncthreads();
  if ((threadIdx.x & 63) == 0) sbuf[wave] = v;
  __syncthreads();
  float r = sbuf[0];
  for (int i = 1; i < nw; i++) r = MAXOP ? fmaxf(r, sbuf[i]) : (r + sbuf[i]);
  return r;
}

// ---- K1: blocks <8192: x = LN(emb[sent]+pos) -> bf16.
//          blocks >=8192: transpose+cvt wk/wv (1152 tiles); block 8192 also seeds. ----
__global__ __launch_bounds__(192) void embed_ln_k(const int* __restrict__ sent,
    const float* __restrict__ emb, const float* __restrict__ pos,
    const float* __restrict__ g, const float* __restrict__ be, u16* __restrict__ xout,
    const float* __restrict__ wk, const float* __restrict__ wv,
    u16* __restrict__ wkT, u16* __restrict__ wvT,
    const int* sp, const int* ep, const float* bq, const float* bo,
    const float* b1, const float* b2,
    float* qg, float* oa, float* f1, float* f2, int* gidx) {
  int tid = threadIdx.x;
  int bid = blockIdx.x;
  if (bid >= NTOK) {
    // ---- transcvt role ----
    int t = bid - NTOK;                 // 0..1151
    if (t == 0) {                       // seed (once)
      if (tid < 4) {
        int b = tid >> 1;
        int s = (tid & 1) ? ep[b] : sp[b];
        gidx[tid] = b * SS + s;
      }
      for (int i = tid; i < DD; i += 192) {
        float vq = bq[i], vo = bo[i], v2 = b2[i];
        #pragma unroll
        for (int r = 0; r < 4; r++) {
          qg[r * DD + i] = vq; oa[r * DD + i] = vo; f2[r * DD + i] = v2;
        }
      }
      for (int i = tid; i < FF; i += 192) {
        float v1 = b1[i];
        #pragma unroll
        for (int r = 0; r < 4; r++) f1[r * FF + i] = v1;
      }
    }
    int z = t >= 576;
    int tt = z ? t - 576 : t;
    const float* W = z ? wv : wk;
    u16* WT = z ? wvT : wkT;
    __shared__ float tld[32][33];
    int n0 = (tt % 24) * 32, k0 = (tt / 24) * 32;
    int tx = tid & 31, ty = tid >> 5;   // 32 x 6
    #pragma unroll
    for (int i = 0; i < 6; i++) {
      int row = ty + i * 6;
      if (row < 32)
        tld[row][tx] = W[(size_t)(k0 + row) * DD + n0 + tx];
    }
    __syncthreads();
    #pragma unroll
    for (int i = 0; i < 6; i++) {
      int row = ty + i * 6;
      if (row < 32)
        WT[(size_t)(n0 + row) * DD + k0 + tx] = f2bf(tld[tx][row]);
    }
    return;
  }
  // ---- embed+LN role ----
  __shared__ float sbuf[8];
  int tok = bid;
  int s = tok & (SS - 1);
  int row = sent[tok];
  float4 e = *(const float4*)(emb + (size_t)row * DD + tid * 4);
  float4 p = *(const float4*)(pos + (size_t)s * DD + tid * 4);
  float v0 = e.x + p.x, v1 = e.y + p.y, v2 = e.z + p.z, v3 = e.w + p.w;
  float sum = v0 + v1 + v2 + v3;
  float sq  = v0 * v0 + v1 * v1 + v2 * v2 + v3 * v3;
  sum = blk_reduce<false>(sum, sbuf);
  sq  = blk_reduce<false>(sq, sbuf);
  float mean = sum * (1.f / DD);
  float var  = sq * (1.f / DD) - mean * mean;
  float rstd = rsqrtf(var + 1e-5f);
  float4 gg = *(const float4*)(g + tid * 4);
  float4 bb = *(const float4*)(be + tid * 4);
  float o0 = (v0 - mean) * rstd * gg.x + bb.x;
  float o1 = (v1 - mean) * rstd * gg.y + bb.y;
  float o2 = (v2 - mean) * rstd * gg.z + bb.z;
  float o3 = (v3 - mean) * rstd * gg.w + bb.w;
  u32 lo = (u32)f2bf(o0) | ((u32)f2bf(o1) << 16);
  u32 hi = (u32)f2bf(o2) | ((u32)f2bf(o3) << 16);
  uint2 st; st.x = lo; st.y = hi;
  *(uint2*)(xout + (size_t)tok * DD + tid * 4) = st;
}

// ---- K2: fused K+V projection (m97-style, BK=32), grid (64,13); by==12 -> wq matvec ----
__global__ __launch_bounds__(256) void gemm_kv(const u16* __restrict__ A,
    const u16* __restrict__ wkT, const u16* __restrict__ wvT,
    const float* __restrict__ bkp, const float* __restrict__ bvp,
    u16* __restrict__ kb, u16* __restrict__ vb,
    const float* __restrict__ wqw, const int* __restrict__ gidx,
    float* __restrict__ qg) {
  __shared__ u16 As[128 * 32];
  __shared__ u16 Bs[128 * 32];
  __shared__ float s_in[4 * 64];
  int tid = threadIdx.x;
  if (blockIdx.y == 12) {
    // ---- wq 4-row matvec path (36 blocks; rest idle) ----
    if (blockIdx.x >= 36) return;
    int nc = blockIdx.x % 3, ky = blockIdx.x / 3;
    int rr = tid >> 6, kk0 = tid & 63;
    s_in[rr * 64 + kk0] = bf2f(A[(size_t)gidx[rr] * DD + ky * 64 + kk0]);
    __syncthreads();
    int n = nc * 256 + tid;
    int k0 = ky * 64;
    float a0 = 0.f, a1 = 0.f, a2 = 0.f, a3 = 0.f;
    for (int kk = 0; kk < 64; kk++) {
      float w = wqw[(size_t)(k0 + kk) * DD + n];
      a0 += s_in[kk] * w;
      a1 += s_in[64 + kk] * w;
      a2 += s_in[128 + kk] * w;
      a3 += s_in[192 + kk] * w;
    }
    atomicAdd(&qg[n], a0);
    atomicAdd(&qg[DD + n], a1);
    atomicAdd(&qg[2 * DD + n], a2);
    atomicAdd(&qg[3 * DD + n], a3);
    return;
  }
  const int K = DD, N = DD;
  int which = blockIdx.y >= 6;
  int m0 = blockIdx.x * 128;
  int n0 = (blockIdx.y - (which ? 6 : 0)) * 128;
  const u16* Bt = which ? wvT : wkT;
  const float* bias = which ? bvp : bkp;
  u16* C = which ? vb : kb;
  int lane = tid & 63, wave = tid >> 6;
  int wr = wave >> 1, wc = wave & 1;
  f32x4 acc[4][4] = {};
  int ch0 = wave * 64 + lane;
  int r0 = ch0 >> 2, su0 = ch0 & 3;
  int ch1 = 256 + ch0;
  int r1 = ch1 >> 2, su1 = ch1 & 3;
  const u16* a0p = A  + (size_t)(m0 + r0) * K + su0 * 8;
  const u16* a1p = A  + (size_t)(m0 + r1) * K + su1 * 8;
  const u16* b0p = Bt + (size_t)(n0 + r0) * K + su0 * 8;
  const u16* b1p = Bt + (size_t)(n0 + r1) * K + su1 * 8;
  u16* AsW0 = As + (size_t)(wave * 64) * 8;
  u16* AsW1 = As + (size_t)(256 + wave * 64) * 8;
  u16* BsW0 = Bs + (size_t)(wave * 64) * 8;
  u16* BsW1 = Bs + (size_t)(256 + wave * 64) * 8;
  int fr = lane & 15, fk = (lane >> 4) * 8;
  for (int k0 = 0; k0 < K; k0 += 32) {
    GLDS16(a0p + k0, AsW0);
    GLDS16(a1p + k0, AsW1);
    GLDS16(b0p + k0, BsW0);
    GLDS16(b1p + k0, BsW1);
    __syncthreads();
    bf16x8 af[4], bfr[4];
    #pragma unroll
    for (int i = 0; i < 4; i++)
      af[i] = *(const bf16x8*)(As + ((wr * 64 + i * 16 + fr) << 5) + fk);
    #pragma unroll
    for (int j = 0; j < 4; j++)
      bfr[j] = *(const bf16x8*)(Bs + ((wc * 64 + j * 16 + fr) << 5) + fk);
    #pragma unroll
    for (int i = 0; i < 4; i++)
      #pragma unroll
      for (int j = 0; j < 4; j++)
        acc[i][j] = __builtin_amdgcn_mfma_f32_16x16x32_bf16(af[i], bfr[j], acc[i][j], 0, 0, 0);
    __syncthreads();
  }
  int cr = (lane >> 4) * 4;
  int cc = lane & 15;
  #pragma unroll
  for (int i = 0; i < 4; i++) {
    #pragma unroll
    for (int j = 0; j < 4; j++) {
      int col = n0 + wc * 64 + j * 16 + cc;
      float bvv = bias[col];
      int rowb = m0 + wr * 64 + i * 16 + cr;
      #pragma unroll
      for (int r = 0; r < 4; r++) {
        float v = acc[i][j][r] + bvv;
        C[(size_t)(rowb + r) * N + col] = f2bf(v);
      }
    }
  }
}

// ---- K3: global attention partial, both mention rows of a batch per block ----
__global__ __launch_bounds__(256) void gattn_part(const u16* __restrict__ kb,
    const u16* __restrict__ vb, const float* __restrict__ qg, const int* __restrict__ sent,
    float* __restrict__ part) {
  int sc = blockIdx.x, h = blockIdx.y, b = blockIdx.z;
  __shared__ float pbuf0[256], pbuf1[256];
  __shared__ float ovs0[32][64], ovs1[32][64];
  __shared__ float sbuf[8];
  int tid = threadIdx.x;
  int rsub = tid >> 3, csub = tid & 7;      // 32 row-groups x 8 d-chunks
  float qr0[8], qr1[8];
  #pragma unroll
  for (int j = 0; j < 8; j++) {
    qr0[j] = qg[(2 * b) * DD + h * 64 + csub * 8 + j];
    qr1[j] = qg[(2 * b + 1) * DD + h * 64 + csub * 8 + j];
  }
  size_t kbase = ((size_t)b * SS + sc * 256) * DD + h * 64 + csub * 8;
  #pragma unroll
  for (int pass = 0; pass < 8; pass++) {
    int rowi = pass * 32 + rsub;
    uint4 u = *(const uint4*)(kb + kbase + (size_t)rowi * DD);
    u32 vals[4] = {u.x, u.y, u.z, u.w};
    float d0 = 0.f, d1 = 0.f;
    #pragma unroll
    for (int t = 0; t < 4; t++) {
      float lo = __uint_as_float(vals[t] << 16);
      float hi = __uint_as_float(vals[t] & 0xFFFF0000u);
      d0 += qr0[t * 2] * lo + qr0[t * 2 + 1] * hi;
      d1 += qr1[t * 2] * lo + qr1[t * 2 + 1] * hi;
    }
    d0 += __shfl_xor(d0, 1, 64); d1 += __shfl_xor(d1, 1, 64);
    d0 += __shfl_xor(d0, 2, 64); d1 += __shfl_xor(d1, 2, 64);
    d0 += __shfl_xor(d0, 4, 64); d1 += __shfl_xor(d1, 4, 64);
    if (csub == 0) { pbuf0[rowi] = d0; pbuf1[rowi] = d1; }
  }
  __syncthreads();
  int ok = sent[b * SS + sc * 256 + tid] != 1;
  float s0 = ok ? pbuf0[tid] * 0.125f : -1e9f;
  float s1 = ok ? pbuf1[tid] * 0.125f : -1e9f;
  float m0 = blk_reduce<true>(s0, sbuf);
  float m1 = blk_reduce<true>(s1, sbuf);
  float p0 = expf(s0 - m0);
  float p1 = expf(s1 - m1);
  float ps0 = blk_reduce<false>(p0, sbuf);
  float ps1 = blk_reduce<false>(p1, sbuf);
  pbuf0[tid] = p0;
  pbuf1[tid] = p1;
  __syncthreads();
  float a0[8] = {0,0,0,0,0,0,0,0}, a1[8] = {0,0,0,0,0,0,0,0};
  #pragma unroll
  for (int pass = 0; pass < 8; pass++) {
    int rowi = pass * 32 + rsub;
    uint4 u = *(const uint4*)(vb + kbase + (size_t)rowi * DD);
    u32 vals[4] = {u.x, u.y, u.z, u.w};
    float pw0 = pbuf0[rowi], pw1 = pbuf1[rowi];
    #pragma unroll
    for (int t = 0; t < 4; t++) {
      float lo = __uint_as_float(vals[t] << 16);
      float hi = __uint_as_float(vals[t] & 0xFFFF0000u);
      a0[t * 2]     += pw0 * lo; a0[t * 2 + 1] += pw0 * hi;
      a1[t * 2]     += pw1 * lo; a1[t * 2 + 1] += pw1 * hi;
    }
  }
  #pragma unroll
  for (int j = 0; j < 8; j++) {
    ovs0[rsub][csub * 8 + j] = a0[j];
    ovs1[rsub][csub * 8 + j] = a1[j];
  }
  __syncthreads();
  float* pp0 = part + (((size_t)(2 * b) * HH + h) * 16 + sc) * 66;
  float* pp1 = part + (((size_t)(2 * b + 1) * HH + h) * 16 + sc) * 66;
  if (tid == 0) { pp0[0] = m0; pp0[1] = ps0; pp1[0] = m1; pp1[1] = ps1; }
  if (tid < 64) {
    float o0 = 0.f, o1 = 0.f;
    #pragma unroll
    for (int g2 = 0; g2 < 32; g2++) { o0 += ovs0[g2][tid]; o1 += ovs1[g2][tid]; }
    pp0[2 + tid] = o0;
    pp1[2 + tid] = o1;
  }
}

// ---- K4: wo matvec with fused softmax-combine (blockIdx.y == head) ----
__global__ __launch_bounds__(256) void matvec_wo(const float* __restrict__ W,
    const float* __restrict__ part, float* __restrict__ acc) {
  __shared__ float s_in[4][64];
  int h = blockIdx.y;
  int tid = threadIdx.x;
  int bg = tid >> 6, d = tid & 63;
  const float* pp = part + (((size_t)bg * HH + h) * 16) * 66;
  float M = -1e30f;
  for (int c = 0; c < 16; c++) M = fmaxf(M, pp[c * 66]);
  float Ssum = 0.f, o = 0.f;
  for (int c = 0; c < 16; c++) {
    float e = expf(pp[c * 66] - M);
    Ssum += pp[c * 66 + 1] * e;
    o += pp[c * 66 + 2 + d] * e;
  }
  s_in[bg][d] = o / Ssum;
  __syncthreads();
  int n = blockIdx.x * 256 + tid;
  int k0 = h * 64;
  float a0 = 0.f, a1 = 0.f, a2 = 0.f, a3 = 0.f;
  for (int kk = 0; kk < 64; kk++) {
    float w = W[(size_t)(k0 + kk) * DD + n];
    a0 += s_in[0][kk] * w;
    a1 += s_in[1][kk] * w;
    a2 += s_in[2][kk] * w;
    a3 += s_in[3][kk] * w;
  }
  atomicAdd(&acc[n], a0);
  atomicAdd(&acc[DD + n], a1);
  atomicAdd(&acc[2 * DD + n], a2);
  atomicAdd(&acc[3 * DD + n], a3);
}

// ---- K5: ln1 (recomputed per block) + w1 matvec. grid (12 n, 16 k-chunks of 48) ----
__global__ __launch_bounds__(256) void w1ln_k(const u16* __restrict__ xb,
    const int* __restrict__ gidx, const float* __restrict__ oacc,
    const float* __restrict__ g1, const float* __restrict__ be1,
    float* __restrict__ x1, const float* __restrict__ w1, float* __restrict__ f1a) {
  __shared__ float sbuf[8];
  __shared__ float xr[4][DD];
  int tid = threadIdx.x;
  for (int r = 0; r < 4; r++) {
    float v[3]; float sum = 0.f, sq = 0.f;
    #pragma unroll
    for (int i = 0; i < 3; i++) {
      int d = tid + i * 256;
      float t = bf2f(xb[(size_t)gidx[r] * DD + d]) + oacc[r * DD + d];
      v[i] = t; sum += t; sq += t * t;
    }
    sum = blk_reduce<false>(sum, sbuf);
    sq  = blk_reduce<false>(sq, sbuf);
    float mean = sum * (1.f / DD);
    float rstd = rsqrtf(sq * (1.f / DD) - mean * mean + 1e-5f);
    #pragma unroll
    for (int i = 0; i < 3; i++) {
      int d = tid + i * 256;
      xr[r][d] = (v[i] - mean) * rstd * g1[d] + be1[d];
    }
  }
  __syncthreads();
  if (blockIdx.x == 0 && blockIdx.y == 0) {
    for (int r = 0; r < 4; r++)
      #pragma unroll
      for (int i = 0; i < 3; i++) {
        int d = tid + i * 256;
        x1[r * DD + d] = xr[r][d];
      }
  }
  int k0 = blockIdx.y * 48;
  int n = blockIdx.x * 256 + tid;
  float a0 = 0.f, a1 = 0.f, a2 = 0.f, a3 = 0.f;
  for (int kk = 0; kk < 48; kk++) {
    float w = w1[(size_t)(k0 + kk) * FF + n];
    a0 += xr[0][k0 + kk] * w; a1 += xr[1][k0 + kk] * w;
    a2 += xr[2][k0 + kk] * w; a3 += xr[3][k0 + kk] * w;
  }
  atomicAdd(&f1a[n], a0);
  atomicAdd(&f1a[FF + n], a1);
  atomicAdd(&f1a[2 * FF + n], a2);
  atomicAdd(&f1a[3 * FF + n], a3);
}

// ---- K6: gelu + w2 matvec. grid (3 n, 64 k-chunks of 48) ----
__global__ __launch_bounds__(256) void w2_k(const float* __restrict__ f1a,
    const float* __restrict__ w2, float* __restrict__ f2a) {
  __shared__ float sI[4][48];
  int tid = threadIdx.x;
  int k0 = blockIdx.y * 48;
  for (int idx = tid; idx < 192; idx += 256) {
    int r = idx / 48, kk = idx % 48;
    sI[r][kk] = gelu_f(f1a[(size_t)r * FF + k0 + kk]);
  }
  __syncthreads();
  int n = blockIdx.x * 256 + tid;
  float a0 = 0.f, a1 = 0.f, a2 = 0.f, a3 = 0.f;
  for (int kk = 0; kk < 48; kk++) {
    float w = w2[(size_t)(k0 + kk) * DD + n];
    a0 += sI[0][kk] * w; a1 += sI[1][kk] * w;
    a2 += sI[2][kk] * w; a3 += sI[3][kk] * w;
  }
  atomicAdd(&f2a[n], a0);
  atomicAdd(&f2a[DD + n], a1);
  atomicAdd(&f2a[2 * DD + n], a2);
  atomicAdd(&f2a[3 * DD + n], a3);
}

// ---- K7: ln2 (recomputed per block) + logits. 128 blocks ----
__global__ __launch_bounds__(256) void logits_k(const float* __restrict__ x1,
    const float* __restrict__ f2a, const float* __restrict__ g2,
    const float* __restrict__ be2, const float* __restrict__ ex,
    float* __restrict__ out) {
  __shared__ float sbuf[8];
  __shared__ float hw[4][DD];
  int tid = threadIdx.x;
  for (int r = 0; r < 4; r++) {
    float v[3]; float sum = 0.f, sq = 0.f;
    #pragma unroll
    for (int i = 0; i < 3; i++) {
      int d = tid + i * 256;
      float t = x1[r * DD + d] + f2a[r * DD + d];
      v[i] = t; sum += t; sq += t * t;
    }
    sum = blk_reduce<false>(sum, sbuf);
    sq  = blk_reduce<false>(sq, sbuf);
    float mean = sum * (1.f / DD);
    float rstd = rsqrtf(sq * (1.f / DD) - mean * mean + 1e-5f);
    #pragma unroll
    for (int i = 0; i < 3; i++) {
      int d = tid + i * 256;
      hw[r][d] = (v[i] - mean) * rstd * g2[d] + be2[d];
    }
  }
  __syncthreads();
  int j = blockIdx.x;
  const float* er = ex + (size_t)j * 1536;
  float d0 = 0.f, d1 = 0.f;
  for (int c = tid; c < DD; c += 256) {
    float e0 = er[c], e1 = er[DD + c];
    d0 += hw[0][c] * e0 + hw[1][c] * e1;
    d1 += hw[2][c] * e0 + hw[3][c] * e1;
  }
  d0 = blk_reduce<false>(d0, sbuf);
  d1 = blk_reduce<false>(d1, sbuf);
  if (tid == 0) { out[j] = d0; out[128 + j] = d1; }
}

// ---- K8: loss ----
__global__ __launch_bounds__(128) void loss_k(const float* __restrict__ lg,
    const int* __restrict__ labels, float* __restrict__ out) {
  __shared__ float sbuf[8];
  int tid = threadIdx.x;
  float v0 = lg[tid], v1 = lg[128 + tid];
  float m0 = blk_reduce<true>(v0, sbuf);
  float m1 = blk_reduce<true>(v1, sbuf);
  float s0 = blk_reduce<false>(expf(v0 - m0), sbuf);
  float s1 = blk_reduce<false>(expf(v1 - m1), sbuf);
  if (tid == 0) {
    float lp0 = lg[labels[0]] - m0 - logf(s0);
    float lp1 = lg[128 + labels[1]] - m1 - logf(s1);
    out[256] = -(lp0 + lp1);
  }
}

extern "C" void kernel_launch(void* const* d_in, const int* in_sizes, int n_in,
                              void* d_out, int out_size, void* d_ws, size_t ws_size,
                              hipStream_t stream) {
  const int*   sent = (const int*)d_in[0];
  const int*   sp   = (const int*)d_in[1];
  const int*   ep   = (const int*)d_in[2];
  const int*   lab  = (const int*)d_in[3];
  const float* emb  = (const float*)d_in[4];
  const float* pos  = (const float*)d_in[5];
  const float* ln0g = (const float*)d_in[6];
  const float* ln0b = (const float*)d_in[7];
  const float* wq   = (const float*)d_in[8];
  const float* bq   = (const float*)d_in[9];
  const float* wk   = (const float*)d_in[10];
  const float* bk   = (const float*)d_in[11];
  const float* wv   = (const float*)d_in[12];
  const float* bv   = (const float*)d_in[13];
  const float* wo   = (const float*)d_in[14];
  const float* bo   = (const float*)d_in[15];
  const float* ln1g = (const float*)d_in[16];
  const float* ln1b = (const float*)d_in[17];
  const float* w1   = (const float*)d_in[18];
  const float* b1   = (const float*)d_in[19];
  const float* w2   = (const float*)d_in[20];
  const float* b2   = (const float*)d_in[21];
  const float* ln2g = (const float*)d_in[22];
  const float* ln2b = (const float*)d_in[23];
  const float* ex   = (const float*)d_in[24];
  float* out = (float*)d_out;

  char* basep = (char*)d_ws;
  size_t off = 0;
  auto alloc = [&](size_t bytes) -> void* {
    void* p = basep + off;
    off = (off + bytes + 255) & ~(size_t)255;
    return p;
  };
  u16*   xb   = (u16*)alloc((size_t)NTOK * DD * 2);
  u16*   kb   = (u16*)alloc((size_t)NTOK * DD * 2);
  u16*   vb   = (u16*)alloc((size_t)NTOK * DD * 2);
  u16*   wkT  = (u16*)alloc((size_t)DD * DD * 2);
  u16*   wvT  = (u16*)alloc((size_t)DD * DD * 2);
  float* qg   = (float*)alloc(4 * DD * 4);
  float* oacc = (float*)alloc(4 * DD * 4);
  float* x1   = (float*)alloc(4 * DD * 4);
  float* f1a  = (float*)alloc(4 * FF * 4);
  float* f2a  = (float*)alloc(4 * DD * 4);
  float* part = (float*)alloc((size_t)4 * HH * 16 * 66 * 4);
  int*   gidx = (int*)alloc(64);

  embed_ln_k<<<NTOK + 1152, 192, 0, stream>>>(sent, emb, pos, ln0g, ln0b, xb,
      wk, wv, wkT, wvT, sp, ep, bq, bo, b1, b2, qg, oacc, f1a, f2a, gidx);
  gemm_kv<<<dim3(64, 13), 256, 0, stream>>>(xb, wkT, wvT, bk, bv, kb, vb, wq, gidx, qg);
  gattn_part<<<dim3(16, HH, 2), 256, 0, stream>>>(kb, vb, qg, sent, part);
  matvec_wo<<<dim3(3, HH), 256, 0, stream>>>(wo, part, oacc);
  w1ln_k<<<dim3(12, 16), 256, 0, stream>>>(xb, gidx, oacc, ln1g, ln1b, x1, w1, f1a);
  w2_k<<<dim3(3, 64), 256, 0, stream>>>(f1a, w2, f2a);
  logits_k<<<128, 256, 0, stream>>>(x1, f2a, ln2g, ln2b, ex, out);
  loss_k<<<1, 128, 0, stream>>>(out, lab, out);
}

// Round 12
// 100.323 us; speedup vs baseline: 1.0847x; 1.0489x over previous
//
#include <hip/hip_runtime.h>

typedef unsigned short u16;
typedef unsigned int   u32;
typedef __attribute__((ext_vector_type(8))) short bf16x8;
typedef __attribute__((ext_vector_type(4))) float f32x4;

#define BB 2
#define SS 4096
#define DD 768
#define HH 12
#define FF 3072
#define NTOK 8192

#define GLDS16(gp, lp) __builtin_amdgcn_global_load_lds(                      \
    (const __attribute__((address_space(1))) u32*)(gp),                       \
    (__attribute__((address_space(3))) u32*)(lp), 16, 0, 0)

__device__ __forceinline__ float bf2f(u16 u) {
  return __uint_as_float(((u32)u) << 16);
}
__device__ __forceinline__ u16 f2bf(float f) {
  u32 x = __float_as_uint(f);
  x = x + 0x7FFFu + ((x >> 16) & 1u);
  return (u16)(x >> 16);
}
__device__ __forceinline__ float gelu_f(float v) {
  return 0.5f * v * (1.0f + erff(v * 0.70710678118654752f));
}

template<bool MAXOP>
__device__ __forceinline__ float blk_reduce(float v, float* sbuf) {
  #pragma unroll
  for (int o = 32; o > 0; o >>= 1) {
    float t = __shfl_xor(v, o, 64);
    v = MAXOP ? fmaxf(v, t) : (v + t);
  }
  int wave = threadIdx.x >> 6;
  int nw = blockDim.x >> 6;
  __syncthreads();
  if ((threadIdx.x & 63) == 0) sbuf[wave] = v;
  __syncthreads();
  float r = sbuf[0];
  for (int i = 1; i < nw; i++) r = MAXOP ? fmaxf(r, sbuf[i]) : (r + sbuf[i]);
  return r;
}

// ---- K1: blocks <8192: x = LN(emb[sent]+pos) -> bf16.
//          blocks >=8192: transpose+cvt wk/wv (1152 tiles); block 8192 also seeds. ----
__global__ __launch_bounds__(192) void embed_ln_k(const int* __restrict__ sent,
    const float* __restrict__ emb, const float* __restrict__ pos,
    const float* __restrict__ g, const float* __restrict__ be, u16* __restrict__ xout,
    const float* __restrict__ wk, const float* __restrict__ wv,
    u16* __restrict__ wkT, u16* __restrict__ wvT,
    const int* sp, const int* ep, const float* bq, const float* bo,
    const float* b1, const float* b2,
    float* qg, float* oa, float* f1, float* f2, int* gidx) {
  int tid = threadIdx.x;
  int bid = blockIdx.x;
  if (bid >= NTOK) {
    // ---- transcvt role ----
    int t = bid - NTOK;                 // 0..1151
    if (t == 0) {                       // seed (once)
      if (tid < 4) {
        int b = tid >> 1;
        int s = (tid & 1) ? ep[b] : sp[b];
        gidx[tid] = b * SS + s;
      }
      for (int i = tid; i < DD; i += 192) {
        float vq = bq[i], vo = bo[i], v2 = b2[i];
        #pragma unroll
        for (int r = 0; r < 4; r++) {
          qg[r * DD + i] = vq; oa[r * DD + i] = vo; f2[r * DD + i] = v2;
        }
      }
      for (int i = tid; i < FF; i += 192) {
        float v1 = b1[i];
        #pragma unroll
        for (int r = 0; r < 4; r++) f1[r * FF + i] = v1;
      }
    }
    int z = t >= 576;
    int tt = z ? t - 576 : t;
    const float* W = z ? wv : wk;
    u16* WT = z ? wvT : wkT;
    __shared__ float tld[32][33];
    int n0 = (tt % 24) * 32, k0 = (tt / 24) * 32;
    int tx = tid & 31, ty = tid >> 5;   // 32 x 6
    #pragma unroll
    for (int i = 0; i < 6; i++) {
      int row = ty + i * 6;
      if (row < 32)
        tld[row][tx] = W[(size_t)(k0 + row) * DD + n0 + tx];
    }
    __syncthreads();
    #pragma unroll
    for (int i = 0; i < 6; i++) {
      int row = ty + i * 6;
      if (row < 32)
        WT[(size_t)(n0 + row) * DD + k0 + tx] = f2bf(tld[tx][row]);
    }
    return;
  }
  // ---- embed+LN role ----
  __shared__ float sbuf[8];
  int tok = bid;
  int s = tok & (SS - 1);
  int row = sent[tok];
  float4 e = *(const float4*)(emb + (size_t)row * DD + tid * 4);
  float4 p = *(const float4*)(pos + (size_t)s * DD + tid * 4);
  float v0 = e.x + p.x, v1 = e.y + p.y, v2 = e.z + p.z, v3 = e.w + p.w;
  float sum = v0 + v1 + v2 + v3;
  float sq  = v0 * v0 + v1 * v1 + v2 * v2 + v3 * v3;
  sum = blk_reduce<false>(sum, sbuf);
  sq  = blk_reduce<false>(sq, sbuf);
  float mean = sum * (1.f / DD);
  float var  = sq * (1.f / DD) - mean * mean;
  float rstd = rsqrtf(var + 1e-5f);
  float4 gg = *(const float4*)(g + tid * 4);
  float4 bb = *(const float4*)(be + tid * 4);
  float o0 = (v0 - mean) * rstd * gg.x + bb.x;
  float o1 = (v1 - mean) * rstd * gg.y + bb.y;
  float o2 = (v2 - mean) * rstd * gg.z + bb.z;
  float o3 = (v3 - mean) * rstd * gg.w + bb.w;
  u32 lo = (u32)f2bf(o0) | ((u32)f2bf(o1) << 16);
  u32 hi = (u32)f2bf(o2) | ((u32)f2bf(o3) << 16);
  uint2 st; st.x = lo; st.y = hi;
  *(uint2*)(xout + (size_t)tok * DD + tid * 4) = st;
}

// ---- K2: fused K+V projection, BK=64 + involution LDS swizzle, grid (64,13);
//      by==12 -> wq matvec. Swizzle: LDS phys chunk (r,c) holds global chunk c^(r&7);
//      staged via pre-swizzled per-lane global source (GLDS16 dest linear, rule #21). ----
__global__ __launch_bounds__(256) void gemm_kv(const u16* __restrict__ A,
    const u16* __restrict__ wkT, const u16* __restrict__ wvT,
    const float* __restrict__ bkp, const float* __restrict__ bvp,
    u16* __restrict__ kb, u16* __restrict__ vb,
    const float* __restrict__ wqw, const int* __restrict__ gidx,
    float* __restrict__ qg) {
  __shared__ u16 As[128 * 64];   // 16 KB
  __shared__ u16 Bs[128 * 64];   // 16 KB
  __shared__ float s_in[4 * 64];
  int tid = threadIdx.x;
  if (blockIdx.y == 12) {
    // ---- wq 4-row matvec path (36 blocks; rest idle) ----
    if (blockIdx.x >= 36) return;
    int nc = blockIdx.x % 3, ky = blockIdx.x / 3;
    int rr = tid >> 6, kk0 = tid & 63;
    s_in[rr * 64 + kk0] = bf2f(A[(size_t)gidx[rr] * DD + ky * 64 + kk0]);
    __syncthreads();
    int n = nc * 256 + tid;
    int k0 = ky * 64;
    float a0 = 0.f, a1 = 0.f, a2 = 0.f, a3 = 0.f;
    for (int kk = 0; kk < 64; kk++) {
      float w = wqw[(size_t)(k0 + kk) * DD + n];
      a0 += s_in[kk] * w;
      a1 += s_in[64 + kk] * w;
      a2 += s_in[128 + kk] * w;
      a3 += s_in[192 + kk] * w;
    }
    atomicAdd(&qg[n], a0);
    atomicAdd(&qg[DD + n], a1);
    atomicAdd(&qg[2 * DD + n], a2);
    atomicAdd(&qg[3 * DD + n], a3);
    return;
  }
  const int K = DD, N = DD;
  int which = blockIdx.y >= 6;
  int m0 = blockIdx.x * 128;
  int n0 = (blockIdx.y - (which ? 6 : 0)) * 128;
  const u16* Bt = which ? wvT : wkT;
  const float* bias = which ? bvp : bkp;
  u16* C = which ? vb : kb;
  int lane = tid & 63, wave = tid >> 6;
  int wr = wave >> 1, wc = wave & 1;
  f32x4 acc[4][4] = {};
  // staging: 128x64-u16 tile = 1024 x 16B chunks; thread stages chunks q*256+tid.
  // chunk ch -> row rr=ch>>3, phys chunk cs=ch&7; global source chunk = cs^(rr&7).
  const u16* ap[4]; const u16* bp[4];
  u16* AsW[4]; u16* BsW[4];
  #pragma unroll
  for (int q = 0; q < 4; q++) {
    int ch = q * 256 + tid;
    int rr = ch >> 3, cs = ch & 7;
    int csw = cs ^ (rr & 7);
    ap[q] = A  + (size_t)(m0 + rr) * K + csw * 8;
    bp[q] = Bt + (size_t)(n0 + rr) * K + csw * 8;
    AsW[q] = As + (size_t)(q * 256 + wave * 64) * 8;
    BsW[q] = Bs + (size_t)(q * 256 + wave * 64) * 8;
  }
  int fr = lane & 15;
  for (int k0 = 0; k0 < K; k0 += 64) {
    #pragma unroll
    for (int q = 0; q < 4; q++) {
      GLDS16(ap[q] + k0, AsW[q]);
      GLDS16(bp[q] + k0, BsW[q]);
    }
    __syncthreads();
    #pragma unroll
    for (int ks = 0; ks < 64; ks += 32) {
      int cg = (ks >> 3) + (lane >> 4);   // logical chunk 0..7
      bf16x8 af[4], bfr[4];
      #pragma unroll
      for (int i = 0; i < 4; i++) {
        int r = wr * 64 + i * 16 + fr;
        af[i] = *(const bf16x8*)(As + r * 64 + ((cg ^ (r & 7)) << 3));
      }
      #pragma unroll
      for (int j = 0; j < 4; j++) {
        int r = wc * 64 + j * 16 + fr;
        bfr[j] = *(const bf16x8*)(Bs + r * 64 + ((cg ^ (r & 7)) << 3));
      }
      #pragma unroll
      for (int i = 0; i < 4; i++)
        #pragma unroll
        for (int j = 0; j < 4; j++)
          acc[i][j] = __builtin_amdgcn_mfma_f32_16x16x32_bf16(af[i], bfr[j], acc[i][j], 0, 0, 0);
    }
    __syncthreads();
  }
  int cr = (lane >> 4) * 4;
  int cc = lane & 15;
  #pragma unroll
  for (int i = 0; i < 4; i++) {
    #pragma unroll
    for (int j = 0; j < 4; j++) {
      int col = n0 + wc * 64 + j * 16 + cc;
      float bvv = bias[col];
      int rowb = m0 + wr * 64 + i * 16 + cr;
      #pragma unroll
      for (int r = 0; r < 4; r++) {
        float v = acc[i][j][r] + bvv;
        C[(size_t)(rowb + r) * N + col] = f2bf(v);
      }
    }
  }
}

// ---- K3: global attention partial, both mention rows of a batch per block ----
__global__ __launch_bounds__(256) void gattn_part(const u16* __restrict__ kb,
    const u16* __restrict__ vb, const float* __restrict__ qg, const int* __restrict__ sent,
    float* __restrict__ part) {
  int sc = blockIdx.x, h = blockIdx.y, b = blockIdx.z;
  __shared__ float pbuf0[256], pbuf1[256];
  __shared__ float ovs0[32][64], ovs1[32][64];
  __shared__ float sbuf[8];
  int tid = threadIdx.x;
  int rsub = tid >> 3, csub = tid & 7;      // 32 row-groups x 8 d-chunks
  float qr0[8], qr1[8];
  #pragma unroll
  for (int j = 0; j < 8; j++) {
    qr0[j] = qg[(2 * b) * DD + h * 64 + csub * 8 + j];
    qr1[j] = qg[(2 * b + 1) * DD + h * 64 + csub * 8 + j];
  }
  size_t kbase = ((size_t)b * SS + sc * 256) * DD + h * 64 + csub * 8;
  #pragma unroll
  for (int pass = 0; pass < 8; pass++) {
    int rowi = pass * 32 + rsub;
    uint4 u = *(const uint4*)(kb + kbase + (size_t)rowi * DD);
    u32 vals[4] = {u.x, u.y, u.z, u.w};
    float d0 = 0.f, d1 = 0.f;
    #pragma unroll
    for (int t = 0; t < 4; t++) {
      float lo = __uint_as_float(vals[t] << 16);
      float hi = __uint_as_float(vals[t] & 0xFFFF0000u);
      d0 += qr0[t * 2] * lo + qr0[t * 2 + 1] * hi;
      d1 += qr1[t * 2] * lo + qr1[t * 2 + 1] * hi;
    }
    d0 += __shfl_xor(d0, 1, 64); d1 += __shfl_xor(d1, 1, 64);
    d0 += __shfl_xor(d0, 2, 64); d1 += __shfl_xor(d1, 2, 64);
    d0 += __shfl_xor(d0, 4, 64); d1 += __shfl_xor(d1, 4, 64);
    if (csub == 0) { pbuf0[rowi] = d0; pbuf1[rowi] = d1; }
  }
  __syncthreads();
  int ok = sent[b * SS + sc * 256 + tid] != 1;
  float s0 = ok ? pbuf0[tid] * 0.125f : -1e9f;
  float s1 = ok ? pbuf1[tid] * 0.125f : -1e9f;
  float m0 = blk_reduce<true>(s0, sbuf);
  float m1 = blk_reduce<true>(s1, sbuf);
  float p0 = expf(s0 - m0);
  float p1 = expf(s1 - m1);
  float ps0 = blk_reduce<false>(p0, sbuf);
  float ps1 = blk_reduce<false>(p1, sbuf);
  pbuf0[tid] = p0;
  pbuf1[tid] = p1;
  __syncthreads();
  float a0[8] = {0,0,0,0,0,0,0,0}, a1[8] = {0,0,0,0,0,0,0,0};
  #pragma unroll
  for (int pass = 0; pass < 8; pass++) {
    int rowi = pass * 32 + rsub;
    uint4 u = *(const uint4*)(vb + kbase + (size_t)rowi * DD);
    u32 vals[4] = {u.x, u.y, u.z, u.w};
    float pw0 = pbuf0[rowi], pw1 = pbuf1[rowi];
    #pragma unroll
    for (int t = 0; t < 4; t++) {
      float lo = __uint_as_float(vals[t] << 16);
      float hi = __uint_as_float(vals[t] & 0xFFFF0000u);
      a0[t * 2]     += pw0 * lo; a0[t * 2 + 1] += pw0 * hi;
      a1[t * 2]     += pw1 * lo; a1[t * 2 + 1] += pw1 * hi;
    }
  }
  #pragma unroll
  for (int j = 0; j < 8; j++) {
    ovs0[rsub][csub * 8 + j] = a0[j];
    ovs1[rsub][csub * 8 + j] = a1[j];
  }
  __syncthreads();
  float* pp0 = part + (((size_t)(2 * b) * HH + h) * 16 + sc) * 66;
  float* pp1 = part + (((size_t)(2 * b + 1) * HH + h) * 16 + sc) * 66;
  if (tid == 0) { pp0[0] = m0; pp0[1] = ps0; pp1[0] = m1; pp1[1] = ps1; }
  if (tid < 64) {
    float o0 = 0.f, o1 = 0.f;
    #pragma unroll
    for (int g2 = 0; g2 < 32; g2++) { o0 += ovs0[g2][tid]; o1 += ovs1[g2][tid]; }
    pp0[2 + tid] = o0;
    pp1[2 + tid] = o1;
  }
}

// ---- K4: wo matvec with fused softmax-combine (blockIdx.y == head) ----
__global__ __launch_bounds__(256) void matvec_wo(const float* __restrict__ W,
    const float* __restrict__ part, float* __restrict__ acc) {
  __shared__ float s_in[4][64];
  int h = blockIdx.y;
  int tid = threadIdx.x;
  int bg = tid >> 6, d = tid & 63;
  const float* pp = part + (((size_t)bg * HH + h) * 16) * 66;
  float M = -1e30f;
  for (int c = 0; c < 16; c++) M = fmaxf(M, pp[c * 66]);
  float Ssum = 0.f, o = 0.f;
  for (int c = 0; c < 16; c++) {
    float e = expf(pp[c * 66] - M);
    Ssum += pp[c * 66 + 1] * e;
    o += pp[c * 66 + 2 + d] * e;
  }
  s_in[bg][d] = o / Ssum;
  __syncthreads();
  int n = blockIdx.x * 256 + tid;
  int k0 = h * 64;
  float a0 = 0.f, a1 = 0.f, a2 = 0.f, a3 = 0.f;
  for (int kk = 0; kk < 64; kk++) {
    float w = W[(size_t)(k0 + kk) * DD + n];
    a0 += s_in[0][kk] * w;
    a1 += s_in[1][kk] * w;
    a2 += s_in[2][kk] * w;
    a3 += s_in[3][kk] * w;
  }
  atomicAdd(&acc[n], a0);
  atomicAdd(&acc[DD + n], a1);
  atomicAdd(&acc[2 * DD + n], a2);
  atomicAdd(&acc[3 * DD + n], a3);
}

// ---- K5: ln1 (recomputed per block) + w1 matvec. grid (12 n, 16 k-chunks of 48) ----
__global__ __launch_bounds__(256) void w1ln_k(const u16* __restrict__ xb,
    const int* __restrict__ gidx, const float* __restrict__ oacc,
    const float* __restrict__ g1, const float* __restrict__ be1,
    float* __restrict__ x1, const float* __restrict__ w1, float* __restrict__ f1a) {
  __shared__ float sbuf[8];
  __shared__ float xr[4][DD];
  int tid = threadIdx.x;
  for (int r = 0; r < 4; r++) {
    float v[3]; float sum = 0.f, sq = 0.f;
    #pragma unroll
    for (int i = 0; i < 3; i++) {
      int d = tid + i * 256;
      float t = bf2f(xb[(size_t)gidx[r] * DD + d]) + oacc[r * DD + d];
      v[i] = t; sum += t; sq += t * t;
    }
    sum = blk_reduce<false>(sum, sbuf);
    sq  = blk_reduce<false>(sq, sbuf);
    float mean = sum * (1.f / DD);
    float rstd = rsqrtf(sq * (1.f / DD) - mean * mean + 1e-5f);
    #pragma unroll
    for (int i = 0; i < 3; i++) {
      int d = tid + i * 256;
      xr[r][d] = (v[i] - mean) * rstd * g1[d] + be1[d];
    }
  }
  __syncthreads();
  if (blockIdx.x == 0 && blockIdx.y == 0) {
    for (int r = 0; r < 4; r++)
      #pragma unroll
      for (int i = 0; i < 3; i++) {
        int d = tid + i * 256;
        x1[r * DD + d] = xr[r][d];
      }
  }
  int k0 = blockIdx.y * 48;
  int n = blockIdx.x * 256 + tid;
  float a0 = 0.f, a1 = 0.f, a2 = 0.f, a3 = 0.f;
  for (int kk = 0; kk < 48; kk++) {
    float w = w1[(size_t)(k0 + kk) * FF + n];
    a0 += xr[0][k0 + kk] * w; a1 += xr[1][k0 + kk] * w;
    a2 += xr[2][k0 + kk] * w; a3 += xr[3][k0 + kk] * w;
  }
  atomicAdd(&f1a[n], a0);
  atomicAdd(&f1a[FF + n], a1);
  atomicAdd(&f1a[2 * FF + n], a2);
  atomicAdd(&f1a[3 * FF + n], a3);
}

// ---- K6: gelu + w2 matvec. grid (3 n, 64 k-chunks of 48) ----
__global__ __launch_bounds__(256) void w2_k(const float* __restrict__ f1a,
    const float* __restrict__ w2, float* __restrict__ f2a) {
  __shared__ float sI[4][48];
  int tid = threadIdx.x;
  int k0 = blockIdx.y * 48;
  for (int idx = tid; idx < 192; idx += 256) {
    int r = idx / 48, kk = idx % 48;
    sI[r][kk] = gelu_f(f1a[(size_t)r * FF + k0 + kk]);
  }
  __syncthreads();
  int n = blockIdx.x * 256 + tid;
  float a0 = 0.f, a1 = 0.f, a2 = 0.f, a3 = 0.f;
  for (int kk = 0; kk < 48; kk++) {
    float w = w2[(size_t)(k0 + kk) * DD + n];
    a0 += sI[0][kk] * w; a1 += sI[1][kk] * w;
    a2 += sI[2][kk] * w; a3 += sI[3][kk] * w;
  }
  atomicAdd(&f2a[n], a0);
  atomicAdd(&f2a[DD + n], a1);
  atomicAdd(&f2a[2 * DD + n], a2);
  atomicAdd(&f2a[3 * DD + n], a3);
}

// ---- K7: ln2 (recomputed per block) + logits. 128 blocks ----
__global__ __launch_bounds__(256) void logits_k(const float* __restrict__ x1,
    const float* __restrict__ f2a, const float* __restrict__ g2,
    const float* __restrict__ be2, const float* __restrict__ ex,
    float* __restrict__ out) {
  __shared__ float sbuf[8];
  __shared__ float hw[4][DD];
  int tid = threadIdx.x;
  for (int r = 0; r < 4; r++) {
    float v[3]; float sum = 0.f, sq = 0.f;
    #pragma unroll
    for (int i = 0; i < 3; i++) {
      int d = tid + i * 256;
      float t = x1[r * DD + d] + f2a[r * DD + d];
      v[i] = t; sum += t; sq += t * t;
    }
    sum = blk_reduce<false>(sum, sbuf);
    sq  = blk_reduce<false>(sq, sbuf);
    float mean = sum * (1.f / DD);
    float rstd = rsqrtf(sq * (1.f / DD) - mean * mean + 1e-5f);
    #pragma unroll
    for (int i = 0; i < 3; i++) {
      int d = tid + i * 256;
      hw[r][d] = (v[i] - mean) * rstd * g2[d] + be2[d];
    }
  }
  __syncthreads();
  int j = blockIdx.x;
  const float* er = ex + (size_t)j * 1536;
  float d0 = 0.f, d1 = 0.f;
  for (int c = tid; c < DD; c += 256) {
    float e0 = er[c], e1 = er[DD + c];
    d0 += hw[0][c] * e0 + hw[1][c] * e1;
    d1 += hw[2][c] * e0 + hw[3][c] * e1;
  }
  d0 = blk_reduce<false>(d0, sbuf);
  d1 = blk_reduce<false>(d1, sbuf);
  if (tid == 0) { out[j] = d0; out[128 + j] = d1; }
}

// ---- K8: loss ----
__global__ __launch_bounds__(128) void loss_k(const float* __restrict__ lg,
    const int* __restrict__ labels, float* __restrict__ out) {
  __shared__ float sbuf[8];
  int tid = threadIdx.x;
  float v0 = lg[tid], v1 = lg[128 + tid];
  float m0 = blk_reduce<true>(v0, sbuf);
  float m1 = blk_reduce<true>(v1, sbuf);
  float s0 = blk_reduce<false>(expf(v0 - m0), sbuf);
  float s1 = blk_reduce<false>(expf(v1 - m1), sbuf);
  if (tid == 0) {
    float lp0 = lg[labels[0]] - m0 - logf(s0);
    float lp1 = lg[128 + labels[1]] - m1 - logf(s1);
    out[256] = -(lp0 + lp1);
  }
}

extern "C" void kernel_launch(void* const* d_in, const int* in_sizes, int n_in,
                              void* d_out, int out_size, void* d_ws, size_t ws_size,
                              hipStream_t stream) {
  const int*   sent = (const int*)d_in[0];
  const int*   sp   = (const int*)d_in[1];
  const int*   ep   = (const int*)d_in[2];
  const int*   lab  = (const int*)d_in[3];
  const float* emb  = (const float*)d_in[4];
  const float* pos  = (const float*)d_in[5];
  const float* ln0g = (const float*)d_in[6];
  const float* ln0b = (const float*)d_in[7];
  const float* wq   = (const float*)d_in[8];
  const float* bq   = (const float*)d_in[9];
  const float* wk   = (const float*)d_in[10];
  const float* bk   = (const float*)d_in[11];
  const float* wv   = (const float*)d_in[12];
  const float* bv   = (const float*)d_in[13];
  const float* wo   = (const float*)d_in[14];
  const float* bo   = (const float*)d_in[15];
  const float* ln1g = (const float*)d_in[16];
  const float* ln1b = (const float*)d_in[17];
  const float* w1   = (const float*)d_in[18];
  const float* b1   = (const float*)d_in[19];
  const float* w2   = (const float*)d_in[20];
  const float* b2   = (const float*)d_in[21];
  const float* ln2g = (const float*)d_in[22];
  const float* ln2b = (const float*)d_in[23];
  const float* ex   = (const float*)d_in[24];
  float* out = (float*)d_out;

  char* basep = (char*)d_ws;
  size_t off = 0;
  auto alloc = [&](size_t bytes) -> void* {
    void* p = basep + off;
    off = (off + bytes + 255) & ~(size_t)255;
    return p;
  };
  u16*   xb   = (u16*)alloc((size_t)NTOK * DD * 2);
  u16*   kb   = (u16*)alloc((size_t)NTOK * DD * 2);
  u16*   vb   = (u16*)alloc((size_t)NTOK * DD * 2);
  u16*   wkT  = (u16*)alloc((size_t)DD * DD * 2);
  u16*   wvT  = (u16*)alloc((size_t)DD * DD * 2);
  float* qg   = (float*)alloc(4 * DD * 4);
  float* oacc = (float*)alloc(4 * DD * 4);
  float* x1   = (float*)alloc(4 * DD * 4);
  float* f1a  = (float*)alloc(4 * FF * 4);
  float* f2a  = (float*)alloc(4 * DD * 4);
  float* part = (float*)alloc((size_t)4 * HH * 16 * 66 * 4);
  int*   gidx = (int*)alloc(64);

  embed_ln_k<<<NTOK + 1152, 192, 0, stream>>>(sent, emb, pos, ln0g, ln0b, xb,
      wk, wv, wkT, wvT, sp, ep, bq, bo, b1, b2, qg, oacc, f1a, f2a, gidx);
  gemm_kv<<<dim3(64, 13), 256, 0, stream>>>(xb, wkT, wvT, bk, bv, kb, vb, wq, gidx, qg);
  gattn_part<<<dim3(16, HH, 2), 256, 0, stream>>>(kb, vb, qg, sent, part);
  matvec_wo<<<dim3(3, HH), 256, 0, stream>>>(wo, part, oacc);
  w1ln_k<<<dim3(12, 16), 256, 0, stream>>>(xb, gidx, oacc, ln1g, ln1b, x1, w1, f1a);
  w2_k<<<dim3(3, 64), 256, 0, stream>>>(f1a, w2, f2a);
  logits_k<<<128, 256, 0, stream>>>(x1, f2a, ln2g, ln2b, ex, out);
  loss_k<<<1, 128, 0, stream>>>(out, lab, out);
}